// Round 4
// baseline (881.333 us; speedup 1.0000x reference)
//
#include <hip/hip_runtime.h>
#include <hip/hip_bf16.h>
#include <math.h>

#define B_ 8
#define S_ 1024
#define D_ 768
#define H_ 12
#define DH_ 64
#define FF_ 3072
#define E_ 8
#define CAP_ 2048
#define T_ (B_ * S_)
#define QKVSTR 2304   // fused qkv col count
#define QKSTR 1536    // split q/k row stride

typedef __bf16 bf16_t;
typedef bf16_t bf16x8_t __attribute__((ext_vector_type(8)));
typedef bf16_t bf16x4_t __attribute__((ext_vector_type(4)));
typedef float floatx4_t __attribute__((ext_vector_type(4)));
typedef _Float16 f16_t;
typedef f16_t f16x8_t __attribute__((ext_vector_type(8)));
typedef f16_t f16x4_t __attribute__((ext_vector_type(4)));

// ---------------- bf16 MFMA GEMM: C[M,N] = A[M,K] @ Bt[N,K]^T + bias (opt GELU), bf16 out
#define LSTR 40

__global__ __launch_bounds__(256) void mfma_gemm_kernel(
    const bf16_t* __restrict__ Abase, const bf16_t* __restrict__ Btbase,
    const float* __restrict__ biasbase, bf16_t* __restrict__ Cbase,
    const int* __restrict__ cnt, int cnt_off,
    int M, int N, int K,
    long strideAz, long strideBz, long strideBiasz, long strideCz,
    int apply_gelu)
{
    __shared__ bf16_t As[128 * LSTR];
    __shared__ bf16_t Bs[128 * LSTR];
    const int z = blockIdx.z;
    const int row0 = blockIdx.y * 128;
    const int col0 = blockIdx.x * 128;
    if (cnt && row0 >= cnt[cnt_off + z]) return;
    const bf16_t* A  = Abase + (size_t)z * strideAz;
    const bf16_t* Bt = Btbase + (size_t)z * strideBz;
    const float* bias = biasbase + (size_t)z * strideBiasz;
    bf16_t* C = Cbase + (size_t)z * strideCz;

    const int tid = threadIdx.x;
    const int lane = tid & 63, wave = tid >> 6;
    const int wm = (wave >> 1) * 64, wn = (wave & 1) * 64;
    const int l16 = lane & 15, quad = lane >> 4;

    floatx4_t acc[4][4] = {};

    const int ch0 = tid, ch1 = tid + 256;
    const int r0a = ch0 >> 2, kc0 = (ch0 & 3) * 8;
    const int r1a = ch1 >> 2, kc1 = (ch1 & 3) * 8;

    for (int k0 = 0; k0 < K; k0 += 32) {
        __syncthreads();
        *(int4*)&As[r0a * LSTR + kc0] = *(const int4*)&A[(size_t)(row0 + r0a) * K + k0 + kc0];
        *(int4*)&As[r1a * LSTR + kc1] = *(const int4*)&A[(size_t)(row0 + r1a) * K + k0 + kc1];
        *(int4*)&Bs[r0a * LSTR + kc0] = *(const int4*)&Bt[(size_t)(col0 + r0a) * K + k0 + kc0];
        *(int4*)&Bs[r1a * LSTR + kc1] = *(const int4*)&Bt[(size_t)(col0 + r1a) * K + k0 + kc1];
        __syncthreads();
        bf16x8_t a[4], b[4];
        #pragma unroll
        for (int mt = 0; mt < 4; mt++)
            a[mt] = *(bf16x8_t*)&As[(wm + mt * 16 + l16) * LSTR + quad * 8];
        #pragma unroll
        for (int nt = 0; nt < 4; nt++)
            b[nt] = *(bf16x8_t*)&Bs[(wn + nt * 16 + l16) * LSTR + quad * 8];
        #pragma unroll
        for (int mt = 0; mt < 4; mt++)
            #pragma unroll
            for (int nt = 0; nt < 4; nt++)
                acc[mt][nt] = __builtin_amdgcn_mfma_f32_16x16x32_bf16(a[mt], b[nt], acc[mt][nt], 0, 0, 0);
    }

    #pragma unroll
    for (int mt = 0; mt < 4; mt++) {
        #pragma unroll
        for (int nt = 0; nt < 4; nt++) {
            const int col = col0 + wn + nt * 16 + l16;
            const float bv = bias[col];
            #pragma unroll
            for (int r = 0; r < 4; r++) {
                const int row = row0 + wm + mt * 16 + quad * 4 + r;
                float v = acc[mt][nt][r] + bv;
                if (apply_gelu) v = 0.5f * v * (1.0f + erff(v * 0.70710678118654752f));
                C[(size_t)row * N + col] = (bf16_t)v;
            }
        }
    }
}

// ---------------- split-f16 MFMA GEMM (fp32-equivalent): acc = (Ah+Al)@(Bth+Btl)^T / 64 + bias
__global__ __launch_bounds__(256) void mfma_split_gemm_kernel(
    const f16_t* __restrict__ Ah, const f16_t* __restrict__ Al,
    const f16_t* __restrict__ Bth, const f16_t* __restrict__ Btl,
    const float* __restrict__ bias0, const float* __restrict__ bias1,
    const float* __restrict__ bias2,
    float* __restrict__ C, int K, int N, int mode,
    f16_t* __restrict__ qkh, f16_t* __restrict__ qkl,
    f16_t* __restrict__ vth, f16_t* __restrict__ vtl)
{
    __shared__ f16_t Ash[128 * LSTR], Asl[128 * LSTR];
    __shared__ f16_t Bsh[128 * LSTR], Bsl[128 * LSTR];
    const int row0 = blockIdx.y * 128;
    const int col0 = blockIdx.x * 128;

    const int tid = threadIdx.x;
    const int lane = tid & 63, wave = tid >> 6;
    const int wm = (wave >> 1) * 64, wn = (wave & 1) * 64;
    const int l16 = lane & 15, quad = lane >> 4;

    floatx4_t acc[4][4] = {};

    const int r0a = tid >> 2, kc0 = (tid & 3) * 8;
    const int r1a = r0a + 64;

    for (int k0 = 0; k0 < K; k0 += 32) {
        __syncthreads();
        const size_t a0 = (size_t)(row0 + r0a) * K + k0 + kc0;
        const size_t a1 = (size_t)(row0 + r1a) * K + k0 + kc0;
        const size_t b0 = (size_t)(col0 + r0a) * K + k0 + kc0;
        const size_t b1 = (size_t)(col0 + r1a) * K + k0 + kc0;
        *(int4*)&Ash[r0a * LSTR + kc0] = *(const int4*)&Ah[a0];
        *(int4*)&Ash[r1a * LSTR + kc0] = *(const int4*)&Ah[a1];
        *(int4*)&Asl[r0a * LSTR + kc0] = *(const int4*)&Al[a0];
        *(int4*)&Asl[r1a * LSTR + kc0] = *(const int4*)&Al[a1];
        *(int4*)&Bsh[r0a * LSTR + kc0] = *(const int4*)&Bth[b0];
        *(int4*)&Bsh[r1a * LSTR + kc0] = *(const int4*)&Bth[b1];
        *(int4*)&Bsl[r0a * LSTR + kc0] = *(const int4*)&Btl[b0];
        *(int4*)&Bsl[r1a * LSTR + kc0] = *(const int4*)&Btl[b1];
        __syncthreads();
        f16x8_t bh[4], bl[4];
        #pragma unroll
        for (int nt = 0; nt < 4; nt++) {
            bh[nt] = *(f16x8_t*)&Bsh[(wn + nt * 16 + l16) * LSTR + quad * 8];
            bl[nt] = *(f16x8_t*)&Bsl[(wn + nt * 16 + l16) * LSTR + quad * 8];
        }
        #pragma unroll
        for (int mt = 0; mt < 4; mt++) {
            f16x8_t ah = *(f16x8_t*)&Ash[(wm + mt * 16 + l16) * LSTR + quad * 8];
            f16x8_t al = *(f16x8_t*)&Asl[(wm + mt * 16 + l16) * LSTR + quad * 8];
            #pragma unroll
            for (int nt = 0; nt < 4; nt++) {
                acc[mt][nt] = __builtin_amdgcn_mfma_f32_16x16x32_f16(ah, bh[nt], acc[mt][nt], 0, 0, 0);
                acc[mt][nt] = __builtin_amdgcn_mfma_f32_16x16x32_f16(al, bh[nt], acc[mt][nt], 0, 0, 0);
                acc[mt][nt] = __builtin_amdgcn_mfma_f32_16x16x32_f16(ah, bl[nt], acc[mt][nt], 0, 0, 0);
            }
        }
    }

    const int wsel = col0 / 768;
    const float* bias = (wsel == 0) ? bias0 : (wsel == 1) ? bias1 : bias2;
    const int colsub = col0 % 768;

    if (mode == 1) {
        if (col0 < 1536) {
            // Q/K: split-f16 rows [T,1536]
            #pragma unroll
            for (int mt = 0; mt < 4; mt++) {
                #pragma unroll
                for (int nt = 0; nt < 4; nt++) {
                    const int col = col0 + wn + nt * 16 + l16;
                    const float bv = bias[colsub + wn + nt * 16 + l16];
                    #pragma unroll
                    for (int r = 0; r < 4; r++) {
                        const int row = row0 + wm + mt * 16 + quad * 4 + r;
                        float v = acc[mt][nt][r] * (1.0f / 64.0f) + bv;
                        f16_t hh = (f16_t)v;
                        const size_t o = (size_t)row * QKSTR + col;
                        qkh[o] = hh; qkl[o] = (f16_t)(v - (float)hh);
                    }
                }
            }
        } else {
            // V: transposed per (b,h): vt[((b*H+h)*64+d)*S + s]
            #pragma unroll
            for (int mt = 0; mt < 4; mt++) {
                const int rowb = row0 + wm + mt * 16 + quad * 4;
                const int bb = rowb >> 10, ss = rowb & 1023;
                #pragma unroll
                for (int nt = 0; nt < 4; nt++) {
                    const int d = (col0 - 1536) + wn + nt * 16 + l16;
                    const int hidx = d >> 6, dd = d & 63;
                    const float bv = bias[colsub + wn + nt * 16 + l16];
                    f16x4_t hv, lv;
                    #pragma unroll
                    for (int r = 0; r < 4; r++) {
                        float v = acc[mt][nt][r] * (1.0f / 64.0f) + bv;
                        hv[r] = (f16_t)v; lv[r] = (f16_t)(v - (float)hv[r]);
                    }
                    const size_t o = ((size_t)(bb * H_ + hidx) * DH_ + dd) * S_ + ss;
                    *(f16x4_t*)&vth[o] = hv;
                    *(f16x4_t*)&vtl[o] = lv;
                }
            }
        }
    } else {
        #pragma unroll
        for (int mt = 0; mt < 4; mt++) {
            #pragma unroll
            for (int nt = 0; nt < 4; nt++) {
                const int col = col0 + wn + nt * 16 + l16;
                const float bv = bias[colsub + wn + nt * 16 + l16];
                #pragma unroll
                for (int r = 0; r < 4; r++) {
                    const int row = row0 + wm + mt * 16 + quad * 4 + r;
                    C[(size_t)row * N + col] = acc[mt][nt][r] * (1.0f / 64.0f) + bv;
                }
            }
        }
    }
}

// ---------------- cast fp32 -> f16 hi/lo split (no scale)
__global__ __launch_bounds__(256) void cast_split_kernel(
    const float* __restrict__ src, f16_t* __restrict__ hi, f16_t* __restrict__ lo)
{
    const int i = blockIdx.x * 256 + threadIdx.x;   // each handles 4 floats
    float4 v = ((const float4*)src)[i];
    const float vv[4] = {v.x, v.y, v.z, v.w};
    f16x4_t h, l;
    #pragma unroll
    for (int c = 0; c < 4; c++) {
        f16_t hh = (f16_t)vv[c];
        h[c] = hh; l[c] = (f16_t)(vv[c] - (float)hh);
    }
    ((f16x4_t*)hi)[i] = h;
    ((f16x4_t*)lo)[i] = l;
}

// ---------------- transpose + scale(x64) + f16 hi/lo split: src[R,C] fp32 -> dst[C,R]
__global__ __launch_bounds__(256) void transpose_cast_split_kernel(
    const float* __restrict__ src, f16_t* __restrict__ dsth, f16_t* __restrict__ dstl,
    int R, int C)
{
    __shared__ float tile[32][33];
    const int r0 = blockIdx.y * 32, c0 = blockIdx.x * 32;
    const int tid = threadIdx.x;
    const int tr = tid >> 3, tc4 = (tid & 7) * 4;
    float4 v = *(const float4*)&src[(size_t)(r0 + tr) * C + c0 + tc4];
    tile[tr][tc4 + 0] = v.x * 64.0f; tile[tr][tc4 + 1] = v.y * 64.0f;
    tile[tr][tc4 + 2] = v.z * 64.0f; tile[tr][tc4 + 3] = v.w * 64.0f;
    __syncthreads();
    const int cc = tid >> 3, rr4 = (tid & 7) * 4;
    f16x4_t h, l;
    #pragma unroll
    for (int i = 0; i < 4; i++) {
        float f = tile[rr4 + i][cc];
        f16_t hh = (f16_t)f;
        h[i] = hh; l[i] = (f16_t)(f - (float)hh);
    }
    *(f16x4_t*)&dsth[(size_t)(c0 + cc) * R + r0 + rr4] = h;
    *(f16x4_t*)&dstl[(size_t)(c0 + cc) * R + r0 + rr4] = l;
}

// ---------------- transpose + cast: fp32 src[R,C] -> bf16 dst[C,R], z-batched
__global__ __launch_bounds__(256) void transpose_cast_kernel(
    const float* __restrict__ src, bf16_t* __restrict__ dst, int R, int C)
{
    __shared__ float tile[32][33];
    const size_t zoff = (size_t)blockIdx.z * R * C;
    const float* s = src + zoff;
    bf16_t* d = dst + zoff;
    const int r0 = blockIdx.y * 32, c0 = blockIdx.x * 32;
    const int tid = threadIdx.x;
    const int tr = tid >> 3, tc4 = (tid & 7) * 4;
    float4 v = *(const float4*)&s[(size_t)(r0 + tr) * C + c0 + tc4];
    tile[tr][tc4 + 0] = v.x; tile[tr][tc4 + 1] = v.y;
    tile[tr][tc4 + 2] = v.z; tile[tr][tc4 + 3] = v.w;
    __syncthreads();
    const int cc = tid >> 3, rr4 = (tid & 7) * 4;
    bf16x4_t o;
    #pragma unroll
    for (int i = 0; i < 4; i++) o[i] = (bf16_t)tile[rr4 + i][cc];
    *(bf16x4_t*)&d[(size_t)(c0 + cc) * R + r0 + rr4] = o;
}

// ---------------- flash attention v4: KVBLK=32 -> LDS 29.7KB -> 5 blocks/CU.
// Waves 0-1 stage K, waves 2-3 stage V. P wave-private (no barrier before PV).
#define KVB 32
#define KSTR 72   // K rows: 64 dh + 8 pad (144B, 16B-mult)
#define VSTR 40   // V rows: 32 keys + 8 pad (80B, 16B-mult)
#define PSTR 40   // P rows: 32 keys + 8 pad

__global__ __launch_bounds__(256, 5) void flash_attn_mfma_kernel(
    const f16_t* __restrict__ qkh, const f16_t* __restrict__ qkl,
    const f16_t* __restrict__ vth, const f16_t* __restrict__ vtl,
    const float* __restrict__ mask,
    f16_t* __restrict__ ctxh, f16_t* __restrict__ ctxl)
{
    __shared__ f16_t Kh[KVB * KSTR], Kl[KVB * KSTR];   // rows = key, cols = dh
    __shared__ f16_t Vh[DH_ * VSTR], Vl[DH_ * VSTR];   // rows = d,   cols = key
    __shared__ f16_t Ph[64 * PSTR],  Pl[64 * PSTR];    // rows = q,   cols = key
    // XCD-local decode: all 16 q-tiles of one (b,h) land on the same XCD.
    const int flat = blockIdx.x;
    const int qt = (flat >> 3) & 15;
    const int p  = (flat & 7) + 8 * (flat >> 7);
    const int h = p % H_, b = p / H_;
    const int tid = threadIdx.x;
    const int lane = tid & 63, wave = tid >> 6;
    const int l16 = lane & 15, quad = lane >> 4;
    const int wm = wave * 16;           // wave's 16-query-row strip
    const int q0 = qt * 64;

    // ---- Q fragments in registers (wave-private rows wm..wm+15)
    const size_t qoff = (size_t)(b * S_ + q0 + wm + l16) * QKSTR + h * DH_ + quad * 8;
    f16x8_t qh[2], ql[2];
    qh[0] = *(const f16x8_t*)&qkh[qoff];
    qh[1] = *(const f16x8_t*)&qkh[qoff + 32];
    ql[0] = *(const f16x8_t*)&qkl[qoff];
    ql[1] = *(const f16x8_t*)&qkl[qoff + 32];

    // ---- staging: waves 0-1 -> K (32 rows x 64 f16), waves 2-3 -> V (64 rows x 32 f16)
    const int stv = tid >> 7;          // wave-uniform
    const int t7 = tid & 127;
    const int krow = t7 >> 2, kcol = (t7 & 3) * 16;    // K: 2 int4 at kcol, kcol+8
    const int vrow = t7 >> 1, vcol = (t7 & 1) * 16;    // V: 2 int4 at vcol, vcol+8
    const size_t kbase = (size_t)b * S_ * QKSTR + 768 + (size_t)h * DH_;
    const size_t vbase = (size_t)(b * H_ + h) * DH_ * (size_t)S_;

    int4 pr0h, pr1h, pr0l, pr1l;
    auto prefetch = [&](int k0) {
        if (stv == 0) {
            const size_t g = kbase + (size_t)(k0 + krow) * QKSTR + kcol;
            pr0h = *(const int4*)&qkh[g]; pr1h = *(const int4*)&qkh[g + 8];
            pr0l = *(const int4*)&qkl[g]; pr1l = *(const int4*)&qkl[g + 8];
        } else {
            const size_t g = vbase + (size_t)vrow * S_ + k0 + vcol;
            pr0h = *(const int4*)&vth[g]; pr1h = *(const int4*)&vth[g + 8];
            pr0l = *(const int4*)&vtl[g]; pr1l = *(const int4*)&vtl[g + 8];
        }
    };
    prefetch(0);

    floatx4_t Oacc[4] = {};             // col = nt2*16+l16 (=d), row = wm+quad*4+r (=q)
    float mrun[4], lrun[4];
    #pragma unroll
    for (int i = 0; i < 4; i++) { mrun[i] = -1e30f; lrun[i] = 0.f; }

    for (int kt = 0; kt < S_ / KVB; kt++) {
        __syncthreads();   // prior K/V readers done
        if (stv == 0) {
            f16_t* dh_ = &Kh[krow * KSTR + kcol];
            f16_t* dl_ = &Kl[krow * KSTR + kcol];
            *(int4*)dh_ = pr0h; *(int4*)(dh_ + 8) = pr1h;
            *(int4*)dl_ = pr0l; *(int4*)(dl_ + 8) = pr1l;
        } else {
            f16_t* dh_ = &Vh[vrow * VSTR + vcol];
            f16_t* dl_ = &Vl[vrow * VSTR + vcol];
            *(int4*)dh_ = pr0h; *(int4*)(dh_ + 8) = pr1h;
            *(int4*)dl_ = pr0l; *(int4*)(dl_ + 8) = pr1l;
        }
        __syncthreads();   // staged data visible
        if (kt + 1 < S_ / KVB) prefetch((kt + 1) * KVB);   // overlap with compute

        // ---- S = Q @ K^T (rows q, cols k), 3-product split; 2 col-tiles of 16
        floatx4_t sacc[2] = {};
        __builtin_amdgcn_s_setprio(1);
        #pragma unroll
        for (int ks2 = 0; ks2 < 2; ks2++) {
            const f16x8_t ah = qh[ks2], al = ql[ks2];
            #pragma unroll
            for (int nt = 0; nt < 2; nt++) {
                f16x8_t bh = *(f16x8_t*)&Kh[(nt * 16 + l16) * KSTR + ks2 * 32 + quad * 8];
                f16x8_t bl = *(f16x8_t*)&Kl[(nt * 16 + l16) * KSTR + ks2 * 32 + quad * 8];
                sacc[nt] = __builtin_amdgcn_mfma_f32_16x16x32_f16(ah, bh, sacc[nt], 0, 0, 0);
                sacc[nt] = __builtin_amdgcn_mfma_f32_16x16x32_f16(al, bh, sacc[nt], 0, 0, 0);
                sacc[nt] = __builtin_amdgcn_mfma_f32_16x16x32_f16(ah, bl, sacc[nt], 0, 0, 0);
            }
        }
        __builtin_amdgcn_s_setprio(0);

        const int k0 = kt * KVB;
        float mk[2];
        #pragma unroll
        for (int nt = 0; nt < 2; nt++) mk[nt] = mask[b * S_ + k0 + nt * 16 + l16];

        // ---- online softmax (rows wm+quad*4+r, wave-private), P split to LDS
        #pragma unroll
        for (int r = 0; r < 4; r++) {
            float s0 = sacc[0][r] * 0.125f + mk[0];
            float s1 = sacc[1][r] * 0.125f + mk[1];
            float rmax = fmaxf(s0, s1);
            #pragma unroll
            for (int off = 1; off < 16; off <<= 1) rmax = fmaxf(rmax, __shfl_xor(rmax, off));
            const float mnew = fmaxf(mrun[r], rmax);
            const float alpha = __expf(mrun[r] - mnew);
            mrun[r] = mnew;
            const int row = wm + quad * 4 + r;
            float p0 = __expf(s0 - mnew);
            float p1 = __expf(s1 - mnew);
            f16_t p0h = (f16_t)p0, p1h = (f16_t)p1;
            Ph[row * PSTR + l16] = p0h;
            Pl[row * PSTR + l16] = (f16_t)(p0 - (float)p0h);
            Ph[row * PSTR + 16 + l16] = p1h;
            Pl[row * PSTR + 16 + l16] = (f16_t)(p1 - (float)p1h);
            float rsum = p0 + p1;
            #pragma unroll
            for (int off = 1; off < 16; off <<= 1) rsum += __shfl_xor(rsum, off);
            lrun[r] = lrun[r] * alpha + rsum;
            #pragma unroll
            for (int nt2 = 0; nt2 < 4; nt2++) Oacc[nt2][r] *= alpha;
        }
        // P is wave-private (writer rows == reader rows) -> no barrier needed

        // ---- O += P @ V  (K-dim = 32 keys: single mfma per d-block)
        __builtin_amdgcn_s_setprio(1);
        {
            f16x8_t pah = *(f16x8_t*)&Ph[(wm + l16) * PSTR + quad * 8];
            f16x8_t pal = *(f16x8_t*)&Pl[(wm + l16) * PSTR + quad * 8];
            #pragma unroll
            for (int nt2 = 0; nt2 < 4; nt2++) {
                f16x8_t bh = *(f16x8_t*)&Vh[(nt2 * 16 + l16) * VSTR + quad * 8];
                f16x8_t bl = *(f16x8_t*)&Vl[(nt2 * 16 + l16) * VSTR + quad * 8];
                Oacc[nt2] = __builtin_amdgcn_mfma_f32_16x16x32_f16(pah, bh, Oacc[nt2], 0, 0, 0);
                Oacc[nt2] = __builtin_amdgcn_mfma_f32_16x16x32_f16(pal, bh, Oacc[nt2], 0, 0, 0);
                Oacc[nt2] = __builtin_amdgcn_mfma_f32_16x16x32_f16(pah, bl, Oacc[nt2], 0, 0, 0);
            }
        }
        __builtin_amdgcn_s_setprio(0);
    }

    // ---- epilogue: write ctx pre-split h/l
    float invl[4];
    #pragma unroll
    for (int r = 0; r < 4; r++) invl[r] = 1.0f / lrun[r];
    #pragma unroll
    for (int nt2 = 0; nt2 < 4; nt2++) {
        #pragma unroll
        for (int r = 0; r < 4; r++) {
            const float v = Oacc[nt2][r] * invl[r];
            const f16_t hh = (f16_t)v;
            const size_t o = (size_t)(b * S_ + q0 + wm + quad * 4 + r) * D_ + h * DH_ + nt2 * 16 + l16;
            ctxh[o] = hh;
            ctxl[o] = (f16_t)(v - (float)hh);
        }
    }
}

// ---------------- out[t] = LN(x[t] + y[t]) * g + b
__global__ __launch_bounds__(256) void add_ln_kernel(
    const float* __restrict__ x, const float* __restrict__ y,
    const float* __restrict__ g, const float* __restrict__ bb,
    float* __restrict__ out)
{
    const int t = blockIdx.x;
    const int tid = threadIdx.x;
    __shared__ float red[256];
    float vals[3];
    float lsum = 0.f;
    #pragma unroll
    for (int i = 0; i < 3; i++) {
        int c = tid + i * 256;
        float v = x[(size_t)t * D_ + c] + y[(size_t)t * D_ + c];
        vals[i] = v; lsum += v;
    }
    red[tid] = lsum; __syncthreads();
    for (int off = 128; off > 0; off >>= 1) { if (tid < off) red[tid] += red[tid + off]; __syncthreads(); }
    const float mu = red[0] * (1.0f / D_);
    __syncthreads();
    float lvar = 0.f;
    #pragma unroll
    for (int i = 0; i < 3; i++) { float d = vals[i] - mu; lvar += d * d; }
    red[tid] = lvar; __syncthreads();
    for (int off = 128; off > 0; off >>= 1) { if (tid < off) red[tid] += red[tid + off]; __syncthreads(); }
    const float rstd = rsqrtf(red[0] * (1.0f / D_) + 1e-12f);
    #pragma unroll
    for (int i = 0; i < 3; i++) {
        int c = tid + i * 256;
        out[(size_t)t * D_ + c] = (vals[i] - mu) * rstd * g[c] + bb[c];
    }
}

// ---------------- router: 1 wave per token
__global__ __launch_bounds__(64) void router_kernel(
    const float* __restrict__ att, const float* __restrict__ Wr,
    const float* __restrict__ br, float* __restrict__ gate, int* __restrict__ eidx)
{
    const int t = blockIdx.x;
    const int lane = threadIdx.x;
    float lg[E_] = {};
    for (int d = lane; d < D_; d += 64) {
        float xv = att[(size_t)t * D_ + d];
        #pragma unroll
        for (int e = 0; e < E_; e++) lg[e] += xv * Wr[d * E_ + e];
    }
    #pragma unroll
    for (int off = 32; off > 0; off >>= 1)
        #pragma unroll
        for (int e = 0; e < E_; e++) lg[e] += __shfl_down(lg[e], off);
    if (lane == 0) {
        float mx = -1e30f; int mi = 0;
        #pragma unroll
        for (int e = 0; e < E_; e++) {
            lg[e] += br[e];
            if (lg[e] > mx) { mx = lg[e]; mi = e; }
        }
        float ssum = 0.f;
        #pragma unroll
        for (int e = 0; e < E_; e++) ssum += expf(lg[e] - mx);
        gate[t] = 1.0f / ssum;
        eidx[t] = mi;
    }
}

// ---------------- position-within-expert scan (single block) + per-expert counts
__global__ __launch_bounds__(256) void pos_scan_kernel(
    const int* __restrict__ eidx, const float* __restrict__ gate,
    int* __restrict__ pos, float* __restrict__ scale, int* __restrict__ cnt_out)
{
    __shared__ int cnt[256][E_];
    const int tid = threadIdx.x;
    const int start = tid * (T_ / 256);
    int lc[E_] = {};
    for (int i = 0; i < T_ / 256; i++) lc[eidx[start + i]]++;
    #pragma unroll
    for (int e = 0; e < E_; e++) cnt[tid][e] = lc[e];
    __syncthreads();
    if (tid < E_) {
        int run = 0;
        for (int i = 0; i < 256; i++) { int c = cnt[i][tid]; cnt[i][tid] = run; run += c; }
        cnt_out[tid] = run;
    }
    __syncthreads();
    int off[E_];
    #pragma unroll
    for (int e = 0; e < E_; e++) off[e] = cnt[tid][e];
    for (int i = 0; i < T_ / 256; i++) {
        int tk = start + i;
        int e = eidx[tk];
        int p = off[e]++;
        bool keep = p < CAP_;
        pos[tk] = p < CAP_ - 1 ? p : CAP_ - 1;
        scale[tk] = keep ? gate[tk] : 0.0f;
    }
}

// ---------------- scatter kept tokens into per-expert bf16 buffers
__global__ __launch_bounds__(256) void scatter_kernel(
    const float* __restrict__ att, const int* __restrict__ eidx,
    const int* __restrict__ pos, const float* __restrict__ scale,
    bf16_t* __restrict__ buf)
{
    const int t = blockIdx.x;
    if (scale[t] == 0.0f) return;
    const int tid = threadIdx.x;
    const float* src = att + (size_t)t * D_;
    bf16_t* dst = buf + ((size_t)eidx[t] * CAP_ + pos[t]) * D_;
    for (int i = tid; i < D_; i += 256) dst[i] = (bf16_t)src[i];
}

// ---------------- gather (bf16 y) + residual + final LN
__global__ __launch_bounds__(256) void final_ln_kernel(
    const float* __restrict__ att, const bf16_t* __restrict__ y,
    const int* __restrict__ eidx, const int* __restrict__ pos,
    const float* __restrict__ scale,
    const float* __restrict__ g, const float* __restrict__ bb,
    float* __restrict__ out)
{
    const int t = blockIdx.x;
    const int tid = threadIdx.x;
    __shared__ float red[256];
    const float sc = scale[t];
    const bf16_t* yrow = y + ((size_t)eidx[t] * CAP_ + pos[t]) * D_;
    float vals[3];
    float lsum = 0.f;
    #pragma unroll
    for (int i = 0; i < 3; i++) {
        int c = tid + i * 256;
        float v = att[(size_t)t * D_ + c] + (float)yrow[c] * sc;
        vals[i] = v; lsum += v;
    }
    red[tid] = lsum; __syncthreads();
    for (int off = 128; off > 0; off >>= 1) { if (tid < off) red[tid] += red[tid + off]; __syncthreads(); }
    const float mu = red[0] * (1.0f / D_);
    __syncthreads();
    float lvar = 0.f;
    #pragma unroll
    for (int i = 0; i < 3; i++) { float d = vals[i] - mu; lvar += d * d; }
    red[tid] = lvar; __syncthreads();
    for (int off = 128; off > 0; off >>= 1) { if (tid < off) red[tid] += red[tid + off]; __syncthreads(); }
    const float rstd = rsqrtf(red[0] * (1.0f / D_) + 1e-12f);
    #pragma unroll
    for (int i = 0; i < 3; i++) {
        int c = tid + i * 256;
        out[(size_t)t * D_ + c] = (vals[i] - mu) * rstd * g[c] + bb[c];
    }
}

extern "C" void kernel_launch(void* const* d_in, const int* in_sizes, int n_in,
                              void* d_out, int out_size, void* d_ws, size_t ws_size,
                              hipStream_t stream) {
    const float* x     = (const float*)d_in[0];
    const float* mask  = (const float*)d_in[1];
    const float* Wq    = (const float*)d_in[2];
    const float* bq    = (const float*)d_in[3];
    const float* Wk    = (const float*)d_in[4];
    const float* bk    = (const float*)d_in[5];
    const float* Wv    = (const float*)d_in[6];
    const float* bv    = (const float*)d_in[7];
    const float* Wo    = (const float*)d_in[8];
    const float* bo    = (const float*)d_in[9];
    const float* ln1g  = (const float*)d_in[10];
    const float* ln1b  = (const float*)d_in[11];
    const float* Wr    = (const float*)d_in[12];
    const float* br    = (const float*)d_in[13];
    const float* W1    = (const float*)d_in[14];
    const float* b1    = (const float*)d_in[15];
    const float* W2    = (const float*)d_in[16];
    const float* b2    = (const float*)d_in[17];
    const float* ln2g  = (const float*)d_in[18];
    const float* ln2b  = (const float*)d_in[19];
    float* out = (float*)d_out;

    char* ws = (char*)d_ws;
    const size_t TDB = (size_t)T_ * D_ * 4;              // 25.17 MB
    // ---- attention-phase layout:
    f16_t* qkh  = (f16_t*)(ws);                          // [T,1536] f16  (= TDB bytes)
    f16_t* qkl  = (f16_t*)(ws + TDB);
    f16_t* vth  = (f16_t*)(ws + 2 * TDB);                // [B*H*64, S] f16 (= TDB/2)
    f16_t* vtl  = (f16_t*)(ws + 2 * TDB + TDB / 2);
    f16_t* ctxh = (f16_t*)(ws + 3 * TDB);                // [T,768] f16 (= TDB/2)
    f16_t* ctxl = (f16_t*)(ws + 3 * TDB + TDB / 2);
    float* att_buf = (float*)(ws + 4 * TDB);
    // xh/xl share the ctx slot (dead until flash writes it; GEMM reads xh first)
    f16_t* xh = (f16_t*)(ws + 3 * TDB);
    f16_t* xl = xh + (size_t)T_ * D_;
    // weight splits live in the att slot (att written only at add_ln)
    f16_t* wqkvT_h = (f16_t*)(ws + 4 * TDB);             // [2304,768] f16
    f16_t* wqkvT_l = wqkvT_h + (size_t)QKVSTR * D_;
    f16_t* woT_h   = wqkvT_l + (size_t)QKVSTR * D_;      // [768,768] f16
    f16_t* woT_l   = woT_h + (size_t)D_ * D_;            // total 9.4 MB < TDB
    // proj overlays qkh (dead after flash)
    float* proj_b = (float*)(ws);
    // MoE-phase overlays (dead attention regions):
    bf16_t* W1T = (bf16_t*)(ws);                         // [0, 1.5 TDB)
    bf16_t* W2T = (bf16_t*)(ws + (size_t)E_ * FF_ * D_ * 2);   // [1.5, 3 TDB)
    bf16_t* h_b = (bf16_t*)(ws + (size_t)2 * E_ * FF_ * D_ * 2); // [3, 4 TDB) (2-expert path)
    char*  smallp  = ws + 5 * TDB;
    float* gate_b  = (float*)(smallp);
    int*   eidx_b  = (int*)(smallp + 32768);
    int*   pos_b   = (int*)(smallp + 2 * 32768);
    float* scale_b = (float*)(smallp + 3 * 32768);
    int*   cnt_b   = (int*)(smallp + 4 * 32768);
    bf16_t* buf_b  = (bf16_t*)(smallp + 4 * 32768 + 128);
    bf16_t* y_b    = (bf16_t*)((char*)buf_b + (size_t)E_ * CAP_ * D_ * 2);
    // full-8-expert h buffer (used only if workspace is large enough)
    bf16_t* h8_b   = (bf16_t*)((char*)y_b + (size_t)E_ * CAP_ * D_ * 2);
    const size_t need8 = ((char*)h8_b - ws) + (size_t)E_ * CAP_ * FF_ * 2;

    dim3 blk(256);
    // ---- attention path (split-f16 MFMA, fp32-equivalent precision — feeds the router)
    cast_split_kernel<<<dim3(T_ * D_ / 1024), blk, 0, stream>>>(x, xh, xl);
    transpose_cast_split_kernel<<<dim3(D_ / 32, D_ / 32), blk, 0, stream>>>(
        Wq, wqkvT_h, wqkvT_l, D_, D_);
    transpose_cast_split_kernel<<<dim3(D_ / 32, D_ / 32), blk, 0, stream>>>(
        Wk, wqkvT_h + (size_t)D_ * D_, wqkvT_l + (size_t)D_ * D_, D_, D_);
    transpose_cast_split_kernel<<<dim3(D_ / 32, D_ / 32), blk, 0, stream>>>(
        Wv, wqkvT_h + (size_t)2 * D_ * D_, wqkvT_l + (size_t)2 * D_ * D_, D_, D_);
    transpose_cast_split_kernel<<<dim3(D_ / 32, D_ / 32), blk, 0, stream>>>(
        Wo, woT_h, woT_l, D_, D_);
    // QKV GEMM -> split q/k rows + transposed split V (mode 1)
    mfma_split_gemm_kernel<<<dim3(QKVSTR / 128, T_ / 128), blk, 0, stream>>>(
        xh, xl, wqkvT_h, wqkvT_l, bq, bk, bv, nullptr, D_, QKVSTR,
        1, qkh, qkl, vth, vtl);
    flash_attn_mfma_kernel<<<dim3((S_ / 64) * H_ * B_), blk, 0, stream>>>(
        qkh, qkl, vth, vtl, mask, ctxh, ctxl);
    // proj GEMM (mode 0, fp32 out)
    mfma_split_gemm_kernel<<<dim3(D_ / 128, T_ / 128), blk, 0, stream>>>(
        ctxh, ctxl, woT_h, woT_l, bo, bo, bo, proj_b, D_, D_,
        0, nullptr, nullptr, nullptr, nullptr);
    add_ln_kernel<<<dim3(T_), blk, 0, stream>>>(x, proj_b, ln1g, ln1b, att_buf);
    // ---- routing (fp32)
    router_kernel<<<dim3(T_), dim3(64), 0, stream>>>(att_buf, Wr, br, gate_b, eidx_b);
    pos_scan_kernel<<<dim3(1), blk, 0, stream>>>(eidx_b, gate_b, pos_b, scale_b, cnt_b);
    // ---- weight transpose-casts into dead attention region (safe after add_ln)
    transpose_cast_kernel<<<dim3(FF_ / 32, D_ / 32, E_), blk, 0, stream>>>(W1, W1T, D_, FF_);
    transpose_cast_kernel<<<dim3(D_ / 32, FF_ / 32, E_), blk, 0, stream>>>(W2, W2T, FF_, D_);
    // ---- expert buffers
    hipMemsetAsync(buf_b, 0, (size_t)E_ * CAP_ * D_ * 2, stream);
    scatter_kernel<<<dim3(T_), blk, 0, stream>>>(att_buf, eidx_b, pos_b, scale_b, buf_b);
    // ---- expert FFNs, bf16 MFMA
    if (ws_size >= need8) {
        // all 8 experts in two launches (full-machine grids, no serialization tails)
        mfma_gemm_kernel<<<dim3(FF_ / 128, CAP_ / 128, E_), blk, 0, stream>>>(
            buf_b, W1T, b1, h8_b,
            cnt_b, 0, CAP_, FF_, D_,
            (long)CAP_ * D_, (long)FF_ * D_, (long)FF_, (long)CAP_ * FF_, 1);
        mfma_gemm_kernel<<<dim3(D_ / 128, CAP_ / 128, E_), blk, 0, stream>>>(
            h8_b, W2T, b2, y_b,
            cnt_b, 0, CAP_, D_, FF_,
            (long)CAP_ * FF_, (long)D_ * FF_, (long)D_, (long)CAP_ * D_, 0);
    } else {
        for (int bch = 0; bch < 4; bch++) {
            const int e0 = bch * 2;
            mfma_gemm_kernel<<<dim3(FF_ / 128, CAP_ / 128, 2), blk, 0, stream>>>(
                buf_b + (size_t)e0 * CAP_ * D_, W1T + (size_t)e0 * FF_ * D_,
                b1 + (size_t)e0 * FF_, h_b,
                cnt_b, e0, CAP_, FF_, D_,
                (long)CAP_ * D_, (long)FF_ * D_, (long)FF_, (long)CAP_ * FF_, 1);
            mfma_gemm_kernel<<<dim3(D_ / 128, CAP_ / 128, 2), blk, 0, stream>>>(
                h_b, W2T + (size_t)e0 * D_ * FF_,
                b2 + (size_t)e0 * D_, y_b + (size_t)e0 * CAP_ * D_,
                cnt_b, e0, CAP_, D_, FF_,
                (long)CAP_ * FF_, (long)D_ * FF_, (long)D_, (long)CAP_ * D_, 0);
        }
    }
    // ---- gather + residual + LN2
    final_ln_kernel<<<dim3(T_), blk, 0, stream>>>(att_buf, y_b, eidx_b, pos_b, scale_b, ln2g, ln2b, out);
}

// Round 6
// 816.290 us; speedup vs baseline: 1.0797x; 1.0797x over previous
//
#include <hip/hip_runtime.h>
#include <hip/hip_bf16.h>
#include <math.h>

#define B_ 8
#define S_ 1024
#define D_ 768
#define H_ 12
#define DH_ 64
#define FF_ 3072
#define E_ 8
#define CAP_ 2048
#define T_ (B_ * S_)
#define QKVSTR 2304   // fused qkv col count
#define QKSTR 1536    // split q/k row stride

typedef __bf16 bf16_t;
typedef bf16_t bf16x8_t __attribute__((ext_vector_type(8)));
typedef bf16_t bf16x4_t __attribute__((ext_vector_type(4)));
typedef float floatx4_t __attribute__((ext_vector_type(4)));
typedef _Float16 f16_t;
typedef f16_t f16x8_t __attribute__((ext_vector_type(8)));
typedef f16_t f16x4_t __attribute__((ext_vector_type(4)));

// ---------------- bf16 MFMA GEMM: C[M,N] = A[M,K] @ Bt[N,K]^T + bias (opt GELU), bf16 out
#define LSTR 40

__global__ __launch_bounds__(256) void mfma_gemm_kernel(
    const bf16_t* __restrict__ Abase, const bf16_t* __restrict__ Btbase,
    const float* __restrict__ biasbase, bf16_t* __restrict__ Cbase,
    const int* __restrict__ cnt, int cnt_off,
    int M, int N, int K,
    long strideAz, long strideBz, long strideBiasz, long strideCz,
    int apply_gelu)
{
    __shared__ bf16_t As[128 * LSTR];
    __shared__ bf16_t Bs[128 * LSTR];
    const int z = blockIdx.z;
    const int row0 = blockIdx.y * 128;
    const int col0 = blockIdx.x * 128;
    if (cnt && row0 >= cnt[cnt_off + z]) return;
    const bf16_t* A  = Abase + (size_t)z * strideAz;
    const bf16_t* Bt = Btbase + (size_t)z * strideBz;
    const float* bias = biasbase + (size_t)z * strideBiasz;
    bf16_t* C = Cbase + (size_t)z * strideCz;

    const int tid = threadIdx.x;
    const int lane = tid & 63, wave = tid >> 6;
    const int wm = (wave >> 1) * 64, wn = (wave & 1) * 64;
    const int l16 = lane & 15, quad = lane >> 4;

    floatx4_t acc[4][4] = {};

    const int ch0 = tid, ch1 = tid + 256;
    const int r0a = ch0 >> 2, kc0 = (ch0 & 3) * 8;
    const int r1a = ch1 >> 2, kc1 = (ch1 & 3) * 8;

    for (int k0 = 0; k0 < K; k0 += 32) {
        __syncthreads();
        *(int4*)&As[r0a * LSTR + kc0] = *(const int4*)&A[(size_t)(row0 + r0a) * K + k0 + kc0];
        *(int4*)&As[r1a * LSTR + kc1] = *(const int4*)&A[(size_t)(row0 + r1a) * K + k0 + kc1];
        *(int4*)&Bs[r0a * LSTR + kc0] = *(const int4*)&Bt[(size_t)(col0 + r0a) * K + k0 + kc0];
        *(int4*)&Bs[r1a * LSTR + kc1] = *(const int4*)&Bt[(size_t)(col0 + r1a) * K + k0 + kc1];
        __syncthreads();
        bf16x8_t a[4], b[4];
        #pragma unroll
        for (int mt = 0; mt < 4; mt++)
            a[mt] = *(bf16x8_t*)&As[(wm + mt * 16 + l16) * LSTR + quad * 8];
        #pragma unroll
        for (int nt = 0; nt < 4; nt++)
            b[nt] = *(bf16x8_t*)&Bs[(wn + nt * 16 + l16) * LSTR + quad * 8];
        #pragma unroll
        for (int mt = 0; mt < 4; mt++)
            #pragma unroll
            for (int nt = 0; nt < 4; nt++)
                acc[mt][nt] = __builtin_amdgcn_mfma_f32_16x16x32_bf16(a[mt], b[nt], acc[mt][nt], 0, 0, 0);
    }

    #pragma unroll
    for (int mt = 0; mt < 4; mt++) {
        #pragma unroll
        for (int nt = 0; nt < 4; nt++) {
            const int col = col0 + wn + nt * 16 + l16;
            const float bv = bias[col];
            #pragma unroll
            for (int r = 0; r < 4; r++) {
                const int row = row0 + wm + mt * 16 + quad * 4 + r;
                float v = acc[mt][nt][r] + bv;
                if (apply_gelu) v = 0.5f * v * (1.0f + erff(v * 0.70710678118654752f));
                C[(size_t)row * N + col] = (bf16_t)v;
            }
        }
    }
}

// ---------------- split-f16 MFMA GEMM (fp32-equivalent): acc = (Ah+Al)@(Bth+Btl)^T / 64 + bias
__global__ __launch_bounds__(256) void mfma_split_gemm_kernel(
    const f16_t* __restrict__ Ah, const f16_t* __restrict__ Al,
    const f16_t* __restrict__ Bth, const f16_t* __restrict__ Btl,
    const float* __restrict__ bias0, const float* __restrict__ bias1,
    const float* __restrict__ bias2,
    float* __restrict__ C, int K, int N, int mode,
    f16_t* __restrict__ qkh, f16_t* __restrict__ qkl,
    f16_t* __restrict__ vth, f16_t* __restrict__ vtl)
{
    __shared__ f16_t Ash[128 * LSTR], Asl[128 * LSTR];
    __shared__ f16_t Bsh[128 * LSTR], Bsl[128 * LSTR];
    const int row0 = blockIdx.y * 128;
    const int col0 = blockIdx.x * 128;

    const int tid = threadIdx.x;
    const int lane = tid & 63, wave = tid >> 6;
    const int wm = (wave >> 1) * 64, wn = (wave & 1) * 64;
    const int l16 = lane & 15, quad = lane >> 4;

    floatx4_t acc[4][4] = {};

    const int r0a = tid >> 2, kc0 = (tid & 3) * 8;
    const int r1a = r0a + 64;

    for (int k0 = 0; k0 < K; k0 += 32) {
        __syncthreads();
        const size_t a0 = (size_t)(row0 + r0a) * K + k0 + kc0;
        const size_t a1 = (size_t)(row0 + r1a) * K + k0 + kc0;
        const size_t b0 = (size_t)(col0 + r0a) * K + k0 + kc0;
        const size_t b1 = (size_t)(col0 + r1a) * K + k0 + kc0;
        *(int4*)&Ash[r0a * LSTR + kc0] = *(const int4*)&Ah[a0];
        *(int4*)&Ash[r1a * LSTR + kc0] = *(const int4*)&Ah[a1];
        *(int4*)&Asl[r0a * LSTR + kc0] = *(const int4*)&Al[a0];
        *(int4*)&Asl[r1a * LSTR + kc0] = *(const int4*)&Al[a1];
        *(int4*)&Bsh[r0a * LSTR + kc0] = *(const int4*)&Bth[b0];
        *(int4*)&Bsh[r1a * LSTR + kc0] = *(const int4*)&Bth[b1];
        *(int4*)&Bsl[r0a * LSTR + kc0] = *(const int4*)&Btl[b0];
        *(int4*)&Bsl[r1a * LSTR + kc0] = *(const int4*)&Btl[b1];
        __syncthreads();
        f16x8_t bh[4], bl[4];
        #pragma unroll
        for (int nt = 0; nt < 4; nt++) {
            bh[nt] = *(f16x8_t*)&Bsh[(wn + nt * 16 + l16) * LSTR + quad * 8];
            bl[nt] = *(f16x8_t*)&Bsl[(wn + nt * 16 + l16) * LSTR + quad * 8];
        }
        #pragma unroll
        for (int mt = 0; mt < 4; mt++) {
            f16x8_t ah = *(f16x8_t*)&Ash[(wm + mt * 16 + l16) * LSTR + quad * 8];
            f16x8_t al = *(f16x8_t*)&Asl[(wm + mt * 16 + l16) * LSTR + quad * 8];
            #pragma unroll
            for (int nt = 0; nt < 4; nt++) {
                acc[mt][nt] = __builtin_amdgcn_mfma_f32_16x16x32_f16(ah, bh[nt], acc[mt][nt], 0, 0, 0);
                acc[mt][nt] = __builtin_amdgcn_mfma_f32_16x16x32_f16(al, bh[nt], acc[mt][nt], 0, 0, 0);
                acc[mt][nt] = __builtin_amdgcn_mfma_f32_16x16x32_f16(ah, bl[nt], acc[mt][nt], 0, 0, 0);
            }
        }
    }

    const int wsel = col0 / 768;
    const float* bias = (wsel == 0) ? bias0 : (wsel == 1) ? bias1 : bias2;
    const int colsub = col0 % 768;

    if (mode == 1) {
        if (col0 < 1536) {
            // Q/K: split-f16 rows [T,1536]
            #pragma unroll
            for (int mt = 0; mt < 4; mt++) {
                #pragma unroll
                for (int nt = 0; nt < 4; nt++) {
                    const int col = col0 + wn + nt * 16 + l16;
                    const float bv = bias[colsub + wn + nt * 16 + l16];
                    #pragma unroll
                    for (int r = 0; r < 4; r++) {
                        const int row = row0 + wm + mt * 16 + quad * 4 + r;
                        float v = acc[mt][nt][r] * (1.0f / 64.0f) + bv;
                        f16_t hh = (f16_t)v;
                        const size_t o = (size_t)row * QKSTR + col;
                        qkh[o] = hh; qkl[o] = (f16_t)(v - (float)hh);
                    }
                }
            }
        } else {
            // V: transposed per (b,h): vt[((b*H+h)*64+d)*S + s]
            #pragma unroll
            for (int mt = 0; mt < 4; mt++) {
                const int rowb = row0 + wm + mt * 16 + quad * 4;
                const int bb = rowb >> 10, ss = rowb & 1023;
                #pragma unroll
                for (int nt = 0; nt < 4; nt++) {
                    const int d = (col0 - 1536) + wn + nt * 16 + l16;
                    const int hidx = d >> 6, dd = d & 63;
                    const float bv = bias[colsub + wn + nt * 16 + l16];
                    f16x4_t hv, lv;
                    #pragma unroll
                    for (int r = 0; r < 4; r++) {
                        float v = acc[mt][nt][r] * (1.0f / 64.0f) + bv;
                        hv[r] = (f16_t)v; lv[r] = (f16_t)(v - (float)hv[r]);
                    }
                    const size_t o = ((size_t)(bb * H_ + hidx) * DH_ + dd) * S_ + ss;
                    *(f16x4_t*)&vth[o] = hv;
                    *(f16x4_t*)&vtl[o] = lv;
                }
            }
        }
    } else {
        #pragma unroll
        for (int mt = 0; mt < 4; mt++) {
            #pragma unroll
            for (int nt = 0; nt < 4; nt++) {
                const int col = col0 + wn + nt * 16 + l16;
                const float bv = bias[colsub + wn + nt * 16 + l16];
                #pragma unroll
                for (int r = 0; r < 4; r++) {
                    const int row = row0 + wm + mt * 16 + quad * 4 + r;
                    C[(size_t)row * N + col] = acc[mt][nt][r] * (1.0f / 64.0f) + bv;
                }
            }
        }
    }
}

// ---------------- cast fp32 -> f16 hi/lo split (no scale)
__global__ __launch_bounds__(256) void cast_split_kernel(
    const float* __restrict__ src, f16_t* __restrict__ hi, f16_t* __restrict__ lo)
{
    const int i = blockIdx.x * 256 + threadIdx.x;   // each handles 4 floats
    float4 v = ((const float4*)src)[i];
    const float vv[4] = {v.x, v.y, v.z, v.w};
    f16x4_t h, l;
    #pragma unroll
    for (int c = 0; c < 4; c++) {
        f16_t hh = (f16_t)vv[c];
        h[c] = hh; l[c] = (f16_t)(vv[c] - (float)hh);
    }
    ((f16x4_t*)hi)[i] = h;
    ((f16x4_t*)lo)[i] = l;
}

// ---------------- transpose + scale(x64) + f16 hi/lo split: src[R,C] fp32 -> dst[C,R]
__global__ __launch_bounds__(256) void transpose_cast_split_kernel(
    const float* __restrict__ src, f16_t* __restrict__ dsth, f16_t* __restrict__ dstl,
    int R, int C)
{
    __shared__ float tile[32][33];
    const int r0 = blockIdx.y * 32, c0 = blockIdx.x * 32;
    const int tid = threadIdx.x;
    const int tr = tid >> 3, tc4 = (tid & 7) * 4;
    float4 v = *(const float4*)&src[(size_t)(r0 + tr) * C + c0 + tc4];
    tile[tr][tc4 + 0] = v.x * 64.0f; tile[tr][tc4 + 1] = v.y * 64.0f;
    tile[tr][tc4 + 2] = v.z * 64.0f; tile[tr][tc4 + 3] = v.w * 64.0f;
    __syncthreads();
    const int cc = tid >> 3, rr4 = (tid & 7) * 4;
    f16x4_t h, l;
    #pragma unroll
    for (int i = 0; i < 4; i++) {
        float f = tile[rr4 + i][cc];
        f16_t hh = (f16_t)f;
        h[i] = hh; l[i] = (f16_t)(f - (float)hh);
    }
    *(f16x4_t*)&dsth[(size_t)(c0 + cc) * R + r0 + rr4] = h;
    *(f16x4_t*)&dstl[(size_t)(c0 + cc) * R + r0 + rr4] = l;
}

// ---------------- transpose + cast: fp32 src[R,C] -> bf16 dst[C,R], z-batched
__global__ __launch_bounds__(256) void transpose_cast_kernel(
    const float* __restrict__ src, bf16_t* __restrict__ dst, int R, int C)
{
    __shared__ float tile[32][33];
    const size_t zoff = (size_t)blockIdx.z * R * C;
    const float* s = src + zoff;
    bf16_t* d = dst + zoff;
    const int r0 = blockIdx.y * 32, c0 = blockIdx.x * 32;
    const int tid = threadIdx.x;
    const int tr = tid >> 3, tc4 = (tid & 7) * 4;
    float4 v = *(const float4*)&s[(size_t)(r0 + tr) * C + c0 + tc4];
    tile[tr][tc4 + 0] = v.x; tile[tr][tc4 + 1] = v.y;
    tile[tr][tc4 + 2] = v.z; tile[tr][tc4 + 3] = v.w;
    __syncthreads();
    const int cc = tid >> 3, rr4 = (tid & 7) * 4;
    bf16x4_t o;
    #pragma unroll
    for (int i = 0; i < 4; i++) o[i] = (bf16_t)tile[rr4 + i][cc];
    *(bf16x4_t*)&d[(size_t)(c0 + cc) * R + r0 + rr4] = o;
}

// ---------------- flash attention v5b: v2 structure (KVB=64) + XCD-local grid +
// row-sum fused into PV via a constant ones-row in V (l accumulates in Oacc[4]
// with the same alpha rescale -> no rsum shuffles, no lrun bookkeeping).
#define FSTR 72   // LDS row stride (f16): 144 B rows

__global__ __launch_bounds__(256) void flash_attn_mfma_kernel(
    const f16_t* __restrict__ qkh, const f16_t* __restrict__ qkl,
    const f16_t* __restrict__ vth, const f16_t* __restrict__ vtl,
    const float* __restrict__ mask,
    f16_t* __restrict__ ctxh, f16_t* __restrict__ ctxl)
{
    __shared__ f16_t Kh[64 * FSTR], Kl[64 * FSTR];
    __shared__ f16_t Vh[80 * FSTR], Vl[80 * FSTR];   // rows 0-63 = d; row 64 = ones; 65-79 = 0
    __shared__ f16_t Ph[64 * FSTR], Pl[64 * FSTR];
    // XCD-local decode: all 16 q-tiles of one (b,h) land on the same XCD.
    const int flat = blockIdx.x;
    const int qt = (flat >> 3) & 15;
    const int p  = (flat & 7) + 8 * (flat >> 7);
    const int h = p % H_, b = p / H_;
    const int tid = threadIdx.x;
    const int lane = tid & 63, wave = tid >> 6;
    const int l16 = lane & 15, quad = lane >> 4;
    const int wm = wave * 16;           // wave's 16-query-row strip
    const int q0 = qt * 64;

    // ---- Q fragments in registers (wave-private rows wm..wm+15)
    const size_t qoff = (size_t)(b * S_ + q0 + wm + l16) * QKSTR + h * DH_ + quad * 8;
    f16x8_t qh[2], ql[2];
    qh[0] = *(const f16x8_t*)&qkh[qoff];
    qh[1] = *(const f16x8_t*)&qkh[qoff + 32];
    ql[0] = *(const f16x8_t*)&qkl[qoff];
    ql[1] = *(const f16x8_t*)&qkl[qoff + 32];

    // ---- ones-row region of V (rows 64-79): row 64 = 1.0 (h) / 0.0 (l); rows 65-79 = 0.
    #pragma unroll
    for (int i = 0; i < 4; i++) {
        int idx = i * 256 + tid;                 // 0..1023 = 16 rows x 64 cols
        int rr = 64 + (idx >> 6), cc = idx & 63;
        Vh[rr * FSTR + cc] = (rr == 64) ? (f16_t)1.0f : (f16_t)0.0f;
        Vl[rr * FSTR + cc] = (f16_t)0.0f;
    }

    // ---- staging geometry: 512 int4-chunks per buffer, 2 per thread
    const int r0 = tid >> 3, s0 = (tid & 7) * 8;          // rows 0..31
    const int r1 = r0 + 32, s1 = s0;                      // rows 32..63
    const size_t kbase = (size_t)b * S_ * QKSTR + 768 + (size_t)h * DH_;
    const size_t vbase = (size_t)(b * H_ + h) * DH_ * (size_t)S_;

    int4 kr0h, kr1h, kr0l, kr1l, vr0h, vr1h, vr0l, vr1l;
    auto prefetch = [&](int k0) {
        kr0h = *(const int4*)&qkh[kbase + (size_t)(k0 + r0) * QKSTR + s0];
        kr1h = *(const int4*)&qkh[kbase + (size_t)(k0 + r1) * QKSTR + s1];
        kr0l = *(const int4*)&qkl[kbase + (size_t)(k0 + r0) * QKSTR + s0];
        kr1l = *(const int4*)&qkl[kbase + (size_t)(k0 + r1) * QKSTR + s1];
        vr0h = *(const int4*)&vth[vbase + (size_t)r0 * S_ + k0 + s0];
        vr1h = *(const int4*)&vth[vbase + (size_t)r1 * S_ + k0 + s1];
        vr0l = *(const int4*)&vtl[vbase + (size_t)r0 * S_ + k0 + s0];
        vr1l = *(const int4*)&vtl[vbase + (size_t)r1 * S_ + k0 + s1];
    };
    prefetch(0);

    floatx4_t Oacc[5] = {};             // [0..3]: col = nt*16+l16 (=d); [4]: col0 = row-sum l
    float mrun[4];
    #pragma unroll
    for (int i = 0; i < 4; i++) mrun[i] = -1e30f;

    for (int kt = 0; kt < S_ / 64; kt++) {
        __syncthreads();   // prior K/V readers done
        *(int4*)&Kh[r0 * FSTR + s0] = kr0h;
        *(int4*)&Kh[r1 * FSTR + s1] = kr1h;
        *(int4*)&Kl[r0 * FSTR + s0] = kr0l;
        *(int4*)&Kl[r1 * FSTR + s1] = kr1l;
        *(int4*)&Vh[r0 * FSTR + s0] = vr0h;
        *(int4*)&Vh[r1 * FSTR + s1] = vr1h;
        *(int4*)&Vl[r0 * FSTR + s0] = vr0l;
        *(int4*)&Vl[r1 * FSTR + s1] = vr1l;
        __syncthreads();   // staged data visible
        if (kt + 1 < S_ / 64) prefetch((kt + 1) * 64);   // overlap with compute

        // ---- S = Q @ K^T, 3-product split
        floatx4_t sacc[4] = {};
        __builtin_amdgcn_s_setprio(1);
        #pragma unroll
        for (int ks2 = 0; ks2 < 2; ks2++) {
            const f16x8_t ah = qh[ks2], al = ql[ks2];
            #pragma unroll
            for (int nt = 0; nt < 4; nt++) {
                f16x8_t bh = *(f16x8_t*)&Kh[(nt * 16 + l16) * FSTR + ks2 * 32 + quad * 8];
                f16x8_t bl = *(f16x8_t*)&Kl[(nt * 16 + l16) * FSTR + ks2 * 32 + quad * 8];
                sacc[nt] = __builtin_amdgcn_mfma_f32_16x16x32_f16(ah, bh, sacc[nt], 0, 0, 0);
                sacc[nt] = __builtin_amdgcn_mfma_f32_16x16x32_f16(al, bh, sacc[nt], 0, 0, 0);
                sacc[nt] = __builtin_amdgcn_mfma_f32_16x16x32_f16(ah, bl, sacc[nt], 0, 0, 0);
            }
        }
        __builtin_amdgcn_s_setprio(0);

        const int k0 = kt * 64;
        float mk[4];
        #pragma unroll
        for (int nt = 0; nt < 4; nt++) mk[nt] = mask[b * S_ + k0 + nt * 16 + l16];

        // ---- online softmax (rows wm+quad*4+r, wave-private), P split to LDS
        #pragma unroll
        for (int r = 0; r < 4; r++) {
            float s[4];
            float rmax = -1e30f;
            #pragma unroll
            for (int nt = 0; nt < 4; nt++) {
                s[nt] = sacc[nt][r] * 0.125f + mk[nt];
                rmax = fmaxf(rmax, s[nt]);
            }
            #pragma unroll
            for (int off = 1; off < 16; off <<= 1) rmax = fmaxf(rmax, __shfl_xor(rmax, off));
            const float mnew = fmaxf(mrun[r], rmax);
            const float alpha = __expf(mrun[r] - mnew);
            mrun[r] = mnew;
            const int row = wm + quad * 4 + r;
            #pragma unroll
            for (int nt = 0; nt < 4; nt++) {
                float pv = __expf(s[nt] - mnew);
                f16_t ph = (f16_t)pv;
                Ph[row * FSTR + nt * 16 + l16] = ph;
                Pl[row * FSTR + nt * 16 + l16] = (f16_t)(pv - (float)ph);
            }
            #pragma unroll
            for (int nt = 0; nt < 5; nt++) Oacc[nt][r] *= alpha;
        }
        // P is wave-private (writer rows == reader rows) -> no barrier needed

        // ---- O += P @ V ; Oacc[4] accumulates the row-sum via the ones-row
        __builtin_amdgcn_s_setprio(1);
        #pragma unroll
        for (int ks2 = 0; ks2 < 2; ks2++) {
            f16x8_t ah = *(f16x8_t*)&Ph[(wm + l16) * FSTR + ks2 * 32 + quad * 8];
            f16x8_t al = *(f16x8_t*)&Pl[(wm + l16) * FSTR + ks2 * 32 + quad * 8];
            #pragma unroll
            for (int nt = 0; nt < 5; nt++) {
                f16x8_t bh = *(f16x8_t*)&Vh[(nt * 16 + l16) * FSTR + ks2 * 32 + quad * 8];
                Oacc[nt] = __builtin_amdgcn_mfma_f32_16x16x32_f16(ah, bh, Oacc[nt], 0, 0, 0);
                Oacc[nt] = __builtin_amdgcn_mfma_f32_16x16x32_f16(al, bh, Oacc[nt], 0, 0, 0);
                if (nt < 4) {   // ones-row low part is exactly 0 -> skip third product
                    f16x8_t bl = *(f16x8_t*)&Vl[(nt * 16 + l16) * FSTR + ks2 * 32 + quad * 8];
                    Oacc[nt] = __builtin_amdgcn_mfma_f32_16x16x32_f16(ah, bl, Oacc[nt], 0, 0, 0);
                }
            }
        }
        __builtin_amdgcn_s_setprio(0);
    }

    // ---- epilogue: l = Oacc[4] col 0 (lane quad*16); write ctx pre-split h/l
    float invl[4];
    #pragma unroll
    for (int r = 0; r < 4; r++) {
        const float lsum = __shfl(Oacc[4][r], lane & 48);   // broadcast from l16==0 lane
        invl[r] = 1.0f / lsum;
    }
    #pragma unroll
    for (int nt = 0; nt < 4; nt++) {
        #pragma unroll
        for (int r = 0; r < 4; r++) {
            const float v = Oacc[nt][r] * invl[r];
            const f16_t hh = (f16_t)v;
            const size_t o = (size_t)(b * S_ + q0 + wm + quad * 4 + r) * D_ + h * DH_ + nt * 16 + l16;
            ctxh[o] = hh;
            ctxl[o] = (f16_t)(v - (float)hh);
        }
    }
}

// ---------------- out[t] = LN(x[t] + y[t]) * g + b
__global__ __launch_bounds__(256) void add_ln_kernel(
    const float* __restrict__ x, const float* __restrict__ y,
    const float* __restrict__ g, const float* __restrict__ bb,
    float* __restrict__ out)
{
    const int t = blockIdx.x;
    const int tid = threadIdx.x;
    __shared__ float red[256];
    float vals[3];
    float lsum = 0.f;
    #pragma unroll
    for (int i = 0; i < 3; i++) {
        int c = tid + i * 256;
        float v = x[(size_t)t * D_ + c] + y[(size_t)t * D_ + c];
        vals[i] = v; lsum += v;
    }
    red[tid] = lsum; __syncthreads();
    for (int off = 128; off > 0; off >>= 1) { if (tid < off) red[tid] += red[tid + off]; __syncthreads(); }
    const float mu = red[0] * (1.0f / D_);
    __syncthreads();
    float lvar = 0.f;
    #pragma unroll
    for (int i = 0; i < 3; i++) { float d = vals[i] - mu; lvar += d * d; }
    red[tid] = lvar; __syncthreads();
    for (int off = 128; off > 0; off >>= 1) { if (tid < off) red[tid] += red[tid + off]; __syncthreads(); }
    const float rstd = rsqrtf(red[0] * (1.0f / D_) + 1e-12f);
    #pragma unroll
    for (int i = 0; i < 3; i++) {
        int c = tid + i * 256;
        out[(size_t)t * D_ + c] = (vals[i] - mu) * rstd * g[c] + bb[c];
    }
}

// ---------------- router: 1 wave per token
__global__ __launch_bounds__(64) void router_kernel(
    const float* __restrict__ att, const float* __restrict__ Wr,
    const float* __restrict__ br, float* __restrict__ gate, int* __restrict__ eidx)
{
    const int t = blockIdx.x;
    const int lane = threadIdx.x;
    float lg[E_] = {};
    for (int d = lane; d < D_; d += 64) {
        float xv = att[(size_t)t * D_ + d];
        #pragma unroll
        for (int e = 0; e < E_; e++) lg[e] += xv * Wr[d * E_ + e];
    }
    #pragma unroll
    for (int off = 32; off > 0; off >>= 1)
        #pragma unroll
        for (int e = 0; e < E_; e++) lg[e] += __shfl_down(lg[e], off);
    if (lane == 0) {
        float mx = -1e30f; int mi = 0;
        #pragma unroll
        for (int e = 0; e < E_; e++) {
            lg[e] += br[e];
            if (lg[e] > mx) { mx = lg[e]; mi = e; }
        }
        float ssum = 0.f;
        #pragma unroll
        for (int e = 0; e < E_; e++) ssum += expf(lg[e] - mx);
        gate[t] = 1.0f / ssum;
        eidx[t] = mi;
    }
}

// ---------------- position-within-expert scan (single block) + per-expert counts
__global__ __launch_bounds__(256) void pos_scan_kernel(
    const int* __restrict__ eidx, const float* __restrict__ gate,
    int* __restrict__ pos, float* __restrict__ scale, int* __restrict__ cnt_out)
{
    __shared__ int cnt[256][E_];
    const int tid = threadIdx.x;
    const int start = tid * (T_ / 256);
    int lc[E_] = {};
    for (int i = 0; i < T_ / 256; i++) lc[eidx[start + i]]++;
    #pragma unroll
    for (int e = 0; e < E_; e++) cnt[tid][e] = lc[e];
    __syncthreads();
    if (tid < E_) {
        int run = 0;
        for (int i = 0; i < 256; i++) { int c = cnt[i][tid]; cnt[i][tid] = run; run += c; }
        cnt_out[tid] = run;
    }
    __syncthreads();
    int off[E_];
    #pragma unroll
    for (int e = 0; e < E_; e++) off[e] = cnt[tid][e];
    for (int i = 0; i < T_ / 256; i++) {
        int tk = start + i;
        int e = eidx[tk];
        int p = off[e]++;
        bool keep = p < CAP_;
        pos[tk] = p < CAP_ - 1 ? p : CAP_ - 1;
        scale[tk] = keep ? gate[tk] : 0.0f;
    }
}

// ---------------- scatter kept tokens into per-expert bf16 buffers
__global__ __launch_bounds__(256) void scatter_kernel(
    const float* __restrict__ att, const int* __restrict__ eidx,
    const int* __restrict__ pos, const float* __restrict__ scale,
    bf16_t* __restrict__ buf)
{
    const int t = blockIdx.x;
    if (scale[t] == 0.0f) return;
    const int tid = threadIdx.x;
    const float* src = att + (size_t)t * D_;
    bf16_t* dst = buf + ((size_t)eidx[t] * CAP_ + pos[t]) * D_;
    for (int i = tid; i < D_; i += 256) dst[i] = (bf16_t)src[i];
}

// ---------------- gather (bf16 y) + residual + final LN
__global__ __launch_bounds__(256) void final_ln_kernel(
    const float* __restrict__ att, const bf16_t* __restrict__ y,
    const int* __restrict__ eidx, const int* __restrict__ pos,
    const float* __restrict__ scale,
    const float* __restrict__ g, const float* __restrict__ bb,
    float* __restrict__ out)
{
    const int t = blockIdx.x;
    const int tid = threadIdx.x;
    __shared__ float red[256];
    const float sc = scale[t];
    const bf16_t* yrow = y + ((size_t)eidx[t] * CAP_ + pos[t]) * D_;
    float vals[3];
    float lsum = 0.f;
    #pragma unroll
    for (int i = 0; i < 3; i++) {
        int c = tid + i * 256;
        float v = att[(size_t)t * D_ + c] + (float)yrow[c] * sc;
        vals[i] = v; lsum += v;
    }
    red[tid] = lsum; __syncthreads();
    for (int off = 128; off > 0; off >>= 1) { if (tid < off) red[tid] += red[tid + off]; __syncthreads(); }
    const float mu = red[0] * (1.0f / D_);
    __syncthreads();
    float lvar = 0.f;
    #pragma unroll
    for (int i = 0; i < 3; i++) { float d = vals[i] - mu; lvar += d * d; }
    red[tid] = lvar; __syncthreads();
    for (int off = 128; off > 0; off >>= 1) { if (tid < off) red[tid] += red[tid + off]; __syncthreads(); }
    const float rstd = rsqrtf(red[0] * (1.0f / D_) + 1e-12f);
    #pragma unroll
    for (int i = 0; i < 3; i++) {
        int c = tid + i * 256;
        out[(size_t)t * D_ + c] = (vals[i] - mu) * rstd * g[c] + bb[c];
    }
}

extern "C" void kernel_launch(void* const* d_in, const int* in_sizes, int n_in,
                              void* d_out, int out_size, void* d_ws, size_t ws_size,
                              hipStream_t stream) {
    const float* x     = (const float*)d_in[0];
    const float* mask  = (const float*)d_in[1];
    const float* Wq    = (const float*)d_in[2];
    const float* bq    = (const float*)d_in[3];
    const float* Wk    = (const float*)d_in[4];
    const float* bk    = (const float*)d_in[5];
    const float* Wv    = (const float*)d_in[6];
    const float* bv    = (const float*)d_in[7];
    const float* Wo    = (const float*)d_in[8];
    const float* bo    = (const float*)d_in[9];
    const float* ln1g  = (const float*)d_in[10];
    const float* ln1b  = (const float*)d_in[11];
    const float* Wr    = (const float*)d_in[12];
    const float* br    = (const float*)d_in[13];
    const float* W1    = (const float*)d_in[14];
    const float* b1    = (const float*)d_in[15];
    const float* W2    = (const float*)d_in[16];
    const float* b2    = (const float*)d_in[17];
    const float* ln2g  = (const float*)d_in[18];
    const float* ln2b  = (const float*)d_in[19];
    float* out = (float*)d_out;

    char* ws = (char*)d_ws;
    const size_t TDB = (size_t)T_ * D_ * 4;              // 25.17 MB
    // ---- attention-phase layout:
    f16_t* qkh  = (f16_t*)(ws);                          // [T,1536] f16  (= TDB bytes)
    f16_t* qkl  = (f16_t*)(ws + TDB);
    f16_t* vth  = (f16_t*)(ws + 2 * TDB);                // [B*H*64, S] f16 (= TDB/2)
    f16_t* vtl  = (f16_t*)(ws + 2 * TDB + TDB / 2);
    f16_t* ctxh = (f16_t*)(ws + 3 * TDB);                // [T,768] f16 (= TDB/2)
    f16_t* ctxl = (f16_t*)(ws + 3 * TDB + TDB / 2);
    float* att_buf = (float*)(ws + 4 * TDB);
    // xh/xl share the ctx slot (dead until flash writes it; GEMM reads xh first)
    f16_t* xh = (f16_t*)(ws + 3 * TDB);
    f16_t* xl = xh + (size_t)T_ * D_;
    // weight splits live in the att slot (att written only at add_ln)
    f16_t* wqkvT_h = (f16_t*)(ws + 4 * TDB);             // [2304,768] f16
    f16_t* wqkvT_l = wqkvT_h + (size_t)QKVSTR * D_;
    f16_t* woT_h   = wqkvT_l + (size_t)QKVSTR * D_;      // [768,768] f16
    f16_t* woT_l   = woT_h + (size_t)D_ * D_;            // total 9.4 MB < TDB
    // proj overlays qkh (dead after flash)
    float* proj_b = (float*)(ws);
    // MoE-phase overlays (dead attention regions):
    bf16_t* W1T = (bf16_t*)(ws);                         // [0, 1.5 TDB)
    bf16_t* W2T = (bf16_t*)(ws + (size_t)E_ * FF_ * D_ * 2);   // [1.5, 3 TDB)
    bf16_t* h_b = (bf16_t*)(ws + (size_t)2 * E_ * FF_ * D_ * 2); // [3, 4 TDB) (2-expert path)
    char*  smallp  = ws + 5 * TDB;
    float* gate_b  = (float*)(smallp);
    int*   eidx_b  = (int*)(smallp + 32768);
    int*   pos_b   = (int*)(smallp + 2 * 32768);
    float* scale_b = (float*)(smallp + 3 * 32768);
    int*   cnt_b   = (int*)(smallp + 4 * 32768);
    bf16_t* buf_b  = (bf16_t*)(smallp + 4 * 32768 + 128);
    bf16_t* y_b    = (bf16_t*)((char*)buf_b + (size_t)E_ * CAP_ * D_ * 2);
    // full-8-expert h buffer (used only if workspace is large enough)
    bf16_t* h8_b   = (bf16_t*)((char*)y_b + (size_t)E_ * CAP_ * D_ * 2);
    const size_t need8 = ((char*)h8_b - ws) + (size_t)E_ * CAP_ * FF_ * 2;

    dim3 blk(256);
    // ---- attention path (split-f16 MFMA, fp32-equivalent precision — feeds the router)
    cast_split_kernel<<<dim3(T_ * D_ / 1024), blk, 0, stream>>>(x, xh, xl);
    transpose_cast_split_kernel<<<dim3(D_ / 32, D_ / 32), blk, 0, stream>>>(
        Wq, wqkvT_h, wqkvT_l, D_, D_);
    transpose_cast_split_kernel<<<dim3(D_ / 32, D_ / 32), blk, 0, stream>>>(
        Wk, wqkvT_h + (size_t)D_ * D_, wqkvT_l + (size_t)D_ * D_, D_, D_);
    transpose_cast_split_kernel<<<dim3(D_ / 32, D_ / 32), blk, 0, stream>>>(
        Wv, wqkvT_h + (size_t)2 * D_ * D_, wqkvT_l + (size_t)2 * D_ * D_, D_, D_);
    transpose_cast_split_kernel<<<dim3(D_ / 32, D_ / 32), blk, 0, stream>>>(
        Wo, woT_h, woT_l, D_, D_);
    // QKV GEMM -> split q/k rows + transposed split V (mode 1)
    mfma_split_gemm_kernel<<<dim3(QKVSTR / 128, T_ / 128), blk, 0, stream>>>(
        xh, xl, wqkvT_h, wqkvT_l, bq, bk, bv, nullptr, D_, QKVSTR,
        1, qkh, qkl, vth, vtl);
    flash_attn_mfma_kernel<<<dim3((S_ / 64) * H_ * B_), blk, 0, stream>>>(
        qkh, qkl, vth, vtl, mask, ctxh, ctxl);
    // proj GEMM (mode 0, fp32 out)
    mfma_split_gemm_kernel<<<dim3(D_ / 128, T_ / 128), blk, 0, stream>>>(
        ctxh, ctxl, woT_h, woT_l, bo, bo, bo, proj_b, D_, D_,
        0, nullptr, nullptr, nullptr, nullptr);
    add_ln_kernel<<<dim3(T_), blk, 0, stream>>>(x, proj_b, ln1g, ln1b, att_buf);
    // ---- routing (fp32)
    router_kernel<<<dim3(T_), dim3(64), 0, stream>>>(att_buf, Wr, br, gate_b, eidx_b);
    pos_scan_kernel<<<dim3(1), blk, 0, stream>>>(eidx_b, gate_b, pos_b, scale_b, cnt_b);
    // ---- weight transpose-casts into dead attention region (safe after add_ln)
    transpose_cast_kernel<<<dim3(FF_ / 32, D_ / 32, E_), blk, 0, stream>>>(W1, W1T, D_, FF_);
    transpose_cast_kernel<<<dim3(D_ / 32, FF_ / 32, E_), blk, 0, stream>>>(W2, W2T, FF_, D_);
    // ---- expert buffers
    hipMemsetAsync(buf_b, 0, (size_t)E_ * CAP_ * D_ * 2, stream);
    scatter_kernel<<<dim3(T_), blk, 0, stream>>>(att_buf, eidx_b, pos_b, scale_b, buf_b);
    // ---- expert FFNs, bf16 MFMA
    if (ws_size >= need8) {
        // all 8 experts in two launches (full-machine grids, no serialization tails)
        mfma_gemm_kernel<<<dim3(FF_ / 128, CAP_ / 128, E_), blk, 0, stream>>>(
            buf_b, W1T, b1, h8_b,
            cnt_b, 0, CAP_, FF_, D_,
            (long)CAP_ * D_, (long)FF_ * D_, (long)FF_, (long)CAP_ * FF_, 1);
        mfma_gemm_kernel<<<dim3(D_ / 128, CAP_ / 128, E_), blk, 0, stream>>>(
            h8_b, W2T, b2, y_b,
            cnt_b, 0, CAP_, D_, FF_,
            (long)CAP_ * FF_, (long)D_ * FF_, (long)D_, (long)CAP_ * D_, 0);
    } else {
        for (int bch = 0; bch < 4; bch++) {
            const int e0 = bch * 2;
            mfma_gemm_kernel<<<dim3(FF_ / 128, CAP_ / 128, 2), blk, 0, stream>>>(
                buf_b + (size_t)e0 * CAP_ * D_, W1T + (size_t)e0 * FF_ * D_,
                b1 + (size_t)e0 * FF_, h_b,
                cnt_b, e0, CAP_, FF_, D_,
                (long)CAP_ * D_, (long)FF_ * D_, (long)FF_, (long)CAP_ * FF_, 1);
            mfma_gemm_kernel<<<dim3(D_ / 128, CAP_ / 128, 2), blk, 0, stream>>>(
                h_b, W2T + (size_t)e0 * D_ * FF_,
                b2 + (size_t)e0 * D_, y_b + (size_t)e0 * CAP_ * D_,
                cnt_b, e0, CAP_, D_, FF_,
                (long)CAP_ * FF_, (long)D_ * FF_, (long)D_, (long)CAP_ * D_, 0);
        }
    }
    // ---- gather + residual + LN2
    final_ln_kernel<<<dim3(T_), blk, 0, stream>>>(att_buf, y_b, eidx_b, pos_b, scale_b, ln2g, ln2b, out);
}

// Round 7
// 814.636 us; speedup vs baseline: 1.0819x; 1.0020x over previous
//
#include <hip/hip_runtime.h>
#include <hip/hip_bf16.h>
#include <math.h>

#define B_ 8
#define S_ 1024
#define D_ 768
#define H_ 12
#define DH_ 64
#define FF_ 3072
#define E_ 8
#define CAP_ 2048
#define T_ (B_ * S_)
#define QKVSTR 2304   // fused qkv col count
#define QKSTR 1536    // split q/k row stride

typedef __bf16 bf16_t;
typedef bf16_t bf16x8_t __attribute__((ext_vector_type(8)));
typedef bf16_t bf16x4_t __attribute__((ext_vector_type(4)));
typedef float floatx4_t __attribute__((ext_vector_type(4)));
typedef _Float16 f16_t;
typedef f16_t f16x8_t __attribute__((ext_vector_type(8)));
typedef f16_t f16x4_t __attribute__((ext_vector_type(4)));

// ---------------- bf16 MFMA GEMM: C[M,N] = A[M,K] @ Bt[N,K]^T + bias (opt GELU), bf16 out
#define LSTR 40

__global__ __launch_bounds__(256) void mfma_gemm_kernel(
    const bf16_t* __restrict__ Abase, const bf16_t* __restrict__ Btbase,
    const float* __restrict__ biasbase, bf16_t* __restrict__ Cbase,
    const int* __restrict__ cnt, int cnt_off,
    int M, int N, int K,
    long strideAz, long strideBz, long strideBiasz, long strideCz,
    int apply_gelu)
{
    __shared__ bf16_t As[128 * LSTR];
    __shared__ bf16_t Bs[128 * LSTR];
    const int z = blockIdx.z;
    const int row0 = blockIdx.y * 128;
    const int col0 = blockIdx.x * 128;
    if (cnt && row0 >= cnt[cnt_off + z]) return;
    const bf16_t* A  = Abase + (size_t)z * strideAz;
    const bf16_t* Bt = Btbase + (size_t)z * strideBz;
    const float* bias = biasbase + (size_t)z * strideBiasz;
    bf16_t* C = Cbase + (size_t)z * strideCz;

    const int tid = threadIdx.x;
    const int lane = tid & 63, wave = tid >> 6;
    const int wm = (wave >> 1) * 64, wn = (wave & 1) * 64;
    const int l16 = lane & 15, quad = lane >> 4;

    floatx4_t acc[4][4] = {};

    const int ch0 = tid, ch1 = tid + 256;
    const int r0a = ch0 >> 2, kc0 = (ch0 & 3) * 8;
    const int r1a = ch1 >> 2, kc1 = (ch1 & 3) * 8;

    for (int k0 = 0; k0 < K; k0 += 32) {
        __syncthreads();
        *(int4*)&As[r0a * LSTR + kc0] = *(const int4*)&A[(size_t)(row0 + r0a) * K + k0 + kc0];
        *(int4*)&As[r1a * LSTR + kc1] = *(const int4*)&A[(size_t)(row0 + r1a) * K + k0 + kc1];
        *(int4*)&Bs[r0a * LSTR + kc0] = *(const int4*)&Bt[(size_t)(col0 + r0a) * K + k0 + kc0];
        *(int4*)&Bs[r1a * LSTR + kc1] = *(const int4*)&Bt[(size_t)(col0 + r1a) * K + k0 + kc1];
        __syncthreads();
        bf16x8_t a[4], b[4];
        #pragma unroll
        for (int mt = 0; mt < 4; mt++)
            a[mt] = *(bf16x8_t*)&As[(wm + mt * 16 + l16) * LSTR + quad * 8];
        #pragma unroll
        for (int nt = 0; nt < 4; nt++)
            b[nt] = *(bf16x8_t*)&Bs[(wn + nt * 16 + l16) * LSTR + quad * 8];
        #pragma unroll
        for (int mt = 0; mt < 4; mt++)
            #pragma unroll
            for (int nt = 0; nt < 4; nt++)
                acc[mt][nt] = __builtin_amdgcn_mfma_f32_16x16x32_bf16(a[mt], b[nt], acc[mt][nt], 0, 0, 0);
    }

    #pragma unroll
    for (int mt = 0; mt < 4; mt++) {
        #pragma unroll
        for (int nt = 0; nt < 4; nt++) {
            const int col = col0 + wn + nt * 16 + l16;
            const float bv = bias[col];
            #pragma unroll
            for (int r = 0; r < 4; r++) {
                const int row = row0 + wm + mt * 16 + quad * 4 + r;
                float v = acc[mt][nt][r] + bv;
                if (apply_gelu) v = 0.5f * v * (1.0f + erff(v * 0.70710678118654752f));
                C[(size_t)row * N + col] = (bf16_t)v;
            }
        }
    }
}

// ---------------- split-f16 MFMA GEMM (fp32-equivalent): acc = (Ah+Al)@(Bth+Btl)^T / 64 + bias
// 1-D grid with XCD-chunk swizzle: each XCD owns a contiguous range of row-bands,
// so the shared A operand is fetched by one XCD's L2 only (T1; proven on flash r3).
__global__ __launch_bounds__(256) void mfma_split_gemm_kernel(
    const f16_t* __restrict__ Ah, const f16_t* __restrict__ Al,
    const f16_t* __restrict__ Bth, const f16_t* __restrict__ Btl,
    const float* __restrict__ bias0, const float* __restrict__ bias1,
    const float* __restrict__ bias2,
    float* __restrict__ C, int K, int N, int mode, int nbx,
    f16_t* __restrict__ qkh, f16_t* __restrict__ qkl,
    f16_t* __restrict__ vth, f16_t* __restrict__ vtl)
{
    __shared__ f16_t Ash[128 * LSTR], Asl[128 * LSTR];
    __shared__ f16_t Bsh[128 * LSTR], Bsl[128 * LSTR];
    // XCD-chunk decode (gridDim.x divisible by 8)
    const int chunk = gridDim.x >> 3;
    const int p = blockIdx.x;
    const int orig = (p & 7) * chunk + (p >> 3);
    const int bx = orig % nbx, by = orig / nbx;
    const int row0 = by * 128;
    const int col0 = bx * 128;

    const int tid = threadIdx.x;
    const int lane = tid & 63, wave = tid >> 6;
    const int wm = (wave >> 1) * 64, wn = (wave & 1) * 64;
    const int l16 = lane & 15, quad = lane >> 4;

    floatx4_t acc[4][4] = {};

    const int r0a = tid >> 2, kc0 = (tid & 3) * 8;
    const int r1a = r0a + 64;

    for (int k0 = 0; k0 < K; k0 += 32) {
        __syncthreads();
        const size_t a0 = (size_t)(row0 + r0a) * K + k0 + kc0;
        const size_t a1 = (size_t)(row0 + r1a) * K + k0 + kc0;
        const size_t b0 = (size_t)(col0 + r0a) * K + k0 + kc0;
        const size_t b1 = (size_t)(col0 + r1a) * K + k0 + kc0;
        *(int4*)&Ash[r0a * LSTR + kc0] = *(const int4*)&Ah[a0];
        *(int4*)&Ash[r1a * LSTR + kc0] = *(const int4*)&Ah[a1];
        *(int4*)&Asl[r0a * LSTR + kc0] = *(const int4*)&Al[a0];
        *(int4*)&Asl[r1a * LSTR + kc0] = *(const int4*)&Al[a1];
        *(int4*)&Bsh[r0a * LSTR + kc0] = *(const int4*)&Bth[b0];
        *(int4*)&Bsh[r1a * LSTR + kc0] = *(const int4*)&Bth[b1];
        *(int4*)&Bsl[r0a * LSTR + kc0] = *(const int4*)&Btl[b0];
        *(int4*)&Bsl[r1a * LSTR + kc0] = *(const int4*)&Btl[b1];
        __syncthreads();
        f16x8_t bh[4], bl[4];
        #pragma unroll
        for (int nt = 0; nt < 4; nt++) {
            bh[nt] = *(f16x8_t*)&Bsh[(wn + nt * 16 + l16) * LSTR + quad * 8];
            bl[nt] = *(f16x8_t*)&Bsl[(wn + nt * 16 + l16) * LSTR + quad * 8];
        }
        #pragma unroll
        for (int mt = 0; mt < 4; mt++) {
            f16x8_t ah = *(f16x8_t*)&Ash[(wm + mt * 16 + l16) * LSTR + quad * 8];
            f16x8_t al = *(f16x8_t*)&Asl[(wm + mt * 16 + l16) * LSTR + quad * 8];
            #pragma unroll
            for (int nt = 0; nt < 4; nt++) {
                acc[mt][nt] = __builtin_amdgcn_mfma_f32_16x16x32_f16(ah, bh[nt], acc[mt][nt], 0, 0, 0);
                acc[mt][nt] = __builtin_amdgcn_mfma_f32_16x16x32_f16(al, bh[nt], acc[mt][nt], 0, 0, 0);
                acc[mt][nt] = __builtin_amdgcn_mfma_f32_16x16x32_f16(ah, bl[nt], acc[mt][nt], 0, 0, 0);
            }
        }
    }

    const int wsel = col0 / 768;
    const float* bias = (wsel == 0) ? bias0 : (wsel == 1) ? bias1 : bias2;
    const int colsub = col0 % 768;

    if (mode == 1) {
        if (col0 < 1536) {
            // Q/K: split-f16 rows [T,1536]
            #pragma unroll
            for (int mt = 0; mt < 4; mt++) {
                #pragma unroll
                for (int nt = 0; nt < 4; nt++) {
                    const int col = col0 + wn + nt * 16 + l16;
                    const float bv = bias[colsub + wn + nt * 16 + l16];
                    #pragma unroll
                    for (int r = 0; r < 4; r++) {
                        const int row = row0 + wm + mt * 16 + quad * 4 + r;
                        float v = acc[mt][nt][r] * (1.0f / 64.0f) + bv;
                        f16_t hh = (f16_t)v;
                        const size_t o = (size_t)row * QKSTR + col;
                        qkh[o] = hh; qkl[o] = (f16_t)(v - (float)hh);
                    }
                }
            }
        } else {
            // V: transposed per (b,h): vt[((b*H+h)*64+d)*S + s]
            #pragma unroll
            for (int mt = 0; mt < 4; mt++) {
                const int rowb = row0 + wm + mt * 16 + quad * 4;
                const int bb = rowb >> 10, ss = rowb & 1023;
                #pragma unroll
                for (int nt = 0; nt < 4; nt++) {
                    const int d = (col0 - 1536) + wn + nt * 16 + l16;
                    const int hidx = d >> 6, dd = d & 63;
                    const float bv = bias[colsub + wn + nt * 16 + l16];
                    f16x4_t hv, lv;
                    #pragma unroll
                    for (int r = 0; r < 4; r++) {
                        float v = acc[mt][nt][r] * (1.0f / 64.0f) + bv;
                        hv[r] = (f16_t)v; lv[r] = (f16_t)(v - (float)hv[r]);
                    }
                    const size_t o = ((size_t)(bb * H_ + hidx) * DH_ + dd) * S_ + ss;
                    *(f16x4_t*)&vth[o] = hv;
                    *(f16x4_t*)&vtl[o] = lv;
                }
            }
        }
    } else {
        #pragma unroll
        for (int mt = 0; mt < 4; mt++) {
            #pragma unroll
            for (int nt = 0; nt < 4; nt++) {
                const int col = col0 + wn + nt * 16 + l16;
                const float bv = bias[colsub + wn + nt * 16 + l16];
                #pragma unroll
                for (int r = 0; r < 4; r++) {
                    const int row = row0 + wm + mt * 16 + quad * 4 + r;
                    C[(size_t)row * N + col] = acc[mt][nt][r] * (1.0f / 64.0f) + bv;
                }
            }
        }
    }
}

// ---------------- cast fp32 -> f16 hi/lo split (no scale)
__global__ __launch_bounds__(256) void cast_split_kernel(
    const float* __restrict__ src, f16_t* __restrict__ hi, f16_t* __restrict__ lo)
{
    const int i = blockIdx.x * 256 + threadIdx.x;   // each handles 4 floats
    float4 v = ((const float4*)src)[i];
    const float vv[4] = {v.x, v.y, v.z, v.w};
    f16x4_t h, l;
    #pragma unroll
    for (int c = 0; c < 4; c++) {
        f16_t hh = (f16_t)vv[c];
        h[c] = hh; l[c] = (f16_t)(vv[c] - (float)hh);
    }
    ((f16x4_t*)hi)[i] = h;
    ((f16x4_t*)lo)[i] = l;
}

// ---------------- fused 4-way transpose + scale(x64) + f16 hi/lo split (768x768 each):
// z=0..2: Wq/Wk/Wv -> wqkvT + z*D*D ; z=3: Wo -> woT
__global__ __launch_bounds__(256) void transpose_cast_split4_kernel(
    const float* __restrict__ Wq, const float* __restrict__ Wk,
    const float* __restrict__ Wv, const float* __restrict__ Wo,
    f16_t* __restrict__ wqkvT_h, f16_t* __restrict__ wqkvT_l,
    f16_t* __restrict__ woT_h, f16_t* __restrict__ woT_l)
{
    __shared__ float tile[32][33];
    const int z = blockIdx.z;
    const float* src = (z == 0) ? Wq : (z == 1) ? Wk : (z == 2) ? Wv : Wo;
    f16_t* dsth = (z < 3) ? wqkvT_h + (size_t)z * D_ * D_ : woT_h;
    f16_t* dstl = (z < 3) ? wqkvT_l + (size_t)z * D_ * D_ : woT_l;
    const int r0 = blockIdx.y * 32, c0 = blockIdx.x * 32;
    const int tid = threadIdx.x;
    const int tr = tid >> 3, tc4 = (tid & 7) * 4;
    float4 v = *(const float4*)&src[(size_t)(r0 + tr) * D_ + c0 + tc4];
    tile[tr][tc4 + 0] = v.x * 64.0f; tile[tr][tc4 + 1] = v.y * 64.0f;
    tile[tr][tc4 + 2] = v.z * 64.0f; tile[tr][tc4 + 3] = v.w * 64.0f;
    __syncthreads();
    const int cc = tid >> 3, rr4 = (tid & 7) * 4;
    f16x4_t h, l;
    #pragma unroll
    for (int i = 0; i < 4; i++) {
        float f = tile[rr4 + i][cc];
        f16_t hh = (f16_t)f;
        h[i] = hh; l[i] = (f16_t)(f - (float)hh);
    }
    *(f16x4_t*)&dsth[(size_t)(c0 + cc) * D_ + r0 + rr4] = h;
    *(f16x4_t*)&dstl[(size_t)(c0 + cc) * D_ + r0 + rr4] = l;
}

// ---------------- transpose + cast: fp32 src[R,C] -> bf16 dst[C,R], z-batched
__global__ __launch_bounds__(256) void transpose_cast_kernel(
    const float* __restrict__ src, bf16_t* __restrict__ dst, int R, int C)
{
    __shared__ float tile[32][33];
    const size_t zoff = (size_t)blockIdx.z * R * C;
    const float* s = src + zoff;
    bf16_t* d = dst + zoff;
    const int r0 = blockIdx.y * 32, c0 = blockIdx.x * 32;
    const int tid = threadIdx.x;
    const int tr = tid >> 3, tc4 = (tid & 7) * 4;
    float4 v = *(const float4*)&s[(size_t)(r0 + tr) * C + c0 + tc4];
    tile[tr][tc4 + 0] = v.x; tile[tr][tc4 + 1] = v.y;
    tile[tr][tc4 + 2] = v.z; tile[tr][tc4 + 3] = v.w;
    __syncthreads();
    const int cc = tid >> 3, rr4 = (tid & 7) * 4;
    bf16x4_t o;
    #pragma unroll
    for (int i = 0; i < 4; i++) o[i] = (bf16_t)tile[rr4 + i][cc];
    *(bf16x4_t*)&d[(size_t)(c0 + cc) * R + r0 + rr4] = o;
}

// ---------------- flash attention v5b: v2 structure (KVB=64) + XCD-local grid +
// row-sum fused into PV via a constant ones-row in V (l accumulates in Oacc[4]
// with the same alpha rescale -> no rsum shuffles, no lrun bookkeeping).
#define FSTR 72   // LDS row stride (f16): 144 B rows

__global__ __launch_bounds__(256) void flash_attn_mfma_kernel(
    const f16_t* __restrict__ qkh, const f16_t* __restrict__ qkl,
    const f16_t* __restrict__ vth, const f16_t* __restrict__ vtl,
    const float* __restrict__ mask,
    f16_t* __restrict__ ctxh, f16_t* __restrict__ ctxl)
{
    __shared__ f16_t Kh[64 * FSTR], Kl[64 * FSTR];
    __shared__ f16_t Vh[80 * FSTR], Vl[80 * FSTR];   // rows 0-63 = d; row 64 = ones; 65-79 = 0
    __shared__ f16_t Ph[64 * FSTR], Pl[64 * FSTR];
    // XCD-local decode: all 16 q-tiles of one (b,h) land on the same XCD.
    const int flat = blockIdx.x;
    const int qt = (flat >> 3) & 15;
    const int p  = (flat & 7) + 8 * (flat >> 7);
    const int h = p % H_, b = p / H_;
    const int tid = threadIdx.x;
    const int lane = tid & 63, wave = tid >> 6;
    const int l16 = lane & 15, quad = lane >> 4;
    const int wm = wave * 16;           // wave's 16-query-row strip
    const int q0 = qt * 64;

    // ---- Q fragments in registers (wave-private rows wm..wm+15)
    const size_t qoff = (size_t)(b * S_ + q0 + wm + l16) * QKSTR + h * DH_ + quad * 8;
    f16x8_t qh[2], ql[2];
    qh[0] = *(const f16x8_t*)&qkh[qoff];
    qh[1] = *(const f16x8_t*)&qkh[qoff + 32];
    ql[0] = *(const f16x8_t*)&qkl[qoff];
    ql[1] = *(const f16x8_t*)&qkl[qoff + 32];

    // ---- ones-row region of V (rows 64-79): row 64 = 1.0 (h) / 0.0 (l); rows 65-79 = 0.
    #pragma unroll
    for (int i = 0; i < 4; i++) {
        int idx = i * 256 + tid;                 // 0..1023 = 16 rows x 64 cols
        int rr = 64 + (idx >> 6), cc = idx & 63;
        Vh[rr * FSTR + cc] = (rr == 64) ? (f16_t)1.0f : (f16_t)0.0f;
        Vl[rr * FSTR + cc] = (f16_t)0.0f;
    }

    // ---- staging geometry: 512 int4-chunks per buffer, 2 per thread
    const int r0 = tid >> 3, s0 = (tid & 7) * 8;          // rows 0..31
    const int r1 = r0 + 32, s1 = s0;                      // rows 32..63
    const size_t kbase = (size_t)b * S_ * QKSTR + 768 + (size_t)h * DH_;
    const size_t vbase = (size_t)(b * H_ + h) * DH_ * (size_t)S_;

    int4 kr0h, kr1h, kr0l, kr1l, vr0h, vr1h, vr0l, vr1l;
    auto prefetch = [&](int k0) {
        kr0h = *(const int4*)&qkh[kbase + (size_t)(k0 + r0) * QKSTR + s0];
        kr1h = *(const int4*)&qkh[kbase + (size_t)(k0 + r1) * QKSTR + s1];
        kr0l = *(const int4*)&qkl[kbase + (size_t)(k0 + r0) * QKSTR + s0];
        kr1l = *(const int4*)&qkl[kbase + (size_t)(k0 + r1) * QKSTR + s1];
        vr0h = *(const int4*)&vth[vbase + (size_t)r0 * S_ + k0 + s0];
        vr1h = *(const int4*)&vth[vbase + (size_t)r1 * S_ + k0 + s1];
        vr0l = *(const int4*)&vtl[vbase + (size_t)r0 * S_ + k0 + s0];
        vr1l = *(const int4*)&vtl[vbase + (size_t)r1 * S_ + k0 + s1];
    };
    prefetch(0);

    floatx4_t Oacc[5] = {};             // [0..3]: col = nt*16+l16 (=d); [4]: col0 = row-sum l
    float mrun[4];
    #pragma unroll
    for (int i = 0; i < 4; i++) mrun[i] = -1e30f;

    for (int kt = 0; kt < S_ / 64; kt++) {
        __syncthreads();   // prior K/V readers done
        *(int4*)&Kh[r0 * FSTR + s0] = kr0h;
        *(int4*)&Kh[r1 * FSTR + s1] = kr1h;
        *(int4*)&Kl[r0 * FSTR + s0] = kr0l;
        *(int4*)&Kl[r1 * FSTR + s1] = kr1l;
        *(int4*)&Vh[r0 * FSTR + s0] = vr0h;
        *(int4*)&Vh[r1 * FSTR + s1] = vr1h;
        *(int4*)&Vl[r0 * FSTR + s0] = vr0l;
        *(int4*)&Vl[r1 * FSTR + s1] = vr1l;
        __syncthreads();   // staged data visible
        if (kt + 1 < S_ / 64) prefetch((kt + 1) * 64);   // overlap with compute

        // ---- S = Q @ K^T, 3-product split
        floatx4_t sacc[4] = {};
        __builtin_amdgcn_s_setprio(1);
        #pragma unroll
        for (int ks2 = 0; ks2 < 2; ks2++) {
            const f16x8_t ah = qh[ks2], al = ql[ks2];
            #pragma unroll
            for (int nt = 0; nt < 4; nt++) {
                f16x8_t bh = *(f16x8_t*)&Kh[(nt * 16 + l16) * FSTR + ks2 * 32 + quad * 8];
                f16x8_t bl = *(f16x8_t*)&Kl[(nt * 16 + l16) * FSTR + ks2 * 32 + quad * 8];
                sacc[nt] = __builtin_amdgcn_mfma_f32_16x16x32_f16(ah, bh, sacc[nt], 0, 0, 0);
                sacc[nt] = __builtin_amdgcn_mfma_f32_16x16x32_f16(al, bh, sacc[nt], 0, 0, 0);
                sacc[nt] = __builtin_amdgcn_mfma_f32_16x16x32_f16(ah, bl, sacc[nt], 0, 0, 0);
            }
        }
        __builtin_amdgcn_s_setprio(0);

        const int k0 = kt * 64;
        float mk[4];
        #pragma unroll
        for (int nt = 0; nt < 4; nt++) mk[nt] = mask[b * S_ + k0 + nt * 16 + l16];

        // ---- online softmax (rows wm+quad*4+r, wave-private), P split to LDS
        #pragma unroll
        for (int r = 0; r < 4; r++) {
            float s[4];
            float rmax = -1e30f;
            #pragma unroll
            for (int nt = 0; nt < 4; nt++) {
                s[nt] = sacc[nt][r] * 0.125f + mk[nt];
                rmax = fmaxf(rmax, s[nt]);
            }
            #pragma unroll
            for (int off = 1; off < 16; off <<= 1) rmax = fmaxf(rmax, __shfl_xor(rmax, off));
            const float mnew = fmaxf(mrun[r], rmax);
            const float alpha = __expf(mrun[r] - mnew);
            mrun[r] = mnew;
            const int row = wm + quad * 4 + r;
            #pragma unroll
            for (int nt = 0; nt < 4; nt++) {
                float pv = __expf(s[nt] - mnew);
                f16_t ph = (f16_t)pv;
                Ph[row * FSTR + nt * 16 + l16] = ph;
                Pl[row * FSTR + nt * 16 + l16] = (f16_t)(pv - (float)ph);
            }
            #pragma unroll
            for (int nt = 0; nt < 5; nt++) Oacc[nt][r] *= alpha;
        }
        // P is wave-private (writer rows == reader rows) -> no barrier needed

        // ---- O += P @ V ; Oacc[4] accumulates the row-sum via the ones-row
        __builtin_amdgcn_s_setprio(1);
        #pragma unroll
        for (int ks2 = 0; ks2 < 2; ks2++) {
            f16x8_t ah = *(f16x8_t*)&Ph[(wm + l16) * FSTR + ks2 * 32 + quad * 8];
            f16x8_t al = *(f16x8_t*)&Pl[(wm + l16) * FSTR + ks2 * 32 + quad * 8];
            #pragma unroll
            for (int nt = 0; nt < 5; nt++) {
                f16x8_t bh = *(f16x8_t*)&Vh[(nt * 16 + l16) * FSTR + ks2 * 32 + quad * 8];
                Oacc[nt] = __builtin_amdgcn_mfma_f32_16x16x32_f16(ah, bh, Oacc[nt], 0, 0, 0);
                Oacc[nt] = __builtin_amdgcn_mfma_f32_16x16x32_f16(al, bh, Oacc[nt], 0, 0, 0);
                if (nt < 4) {   // ones-row low part is exactly 0 -> skip third product
                    f16x8_t bl = *(f16x8_t*)&Vl[(nt * 16 + l16) * FSTR + ks2 * 32 + quad * 8];
                    Oacc[nt] = __builtin_amdgcn_mfma_f32_16x16x32_f16(ah, bl, Oacc[nt], 0, 0, 0);
                }
            }
        }
        __builtin_amdgcn_s_setprio(0);
    }

    // ---- epilogue: l = Oacc[4] col 0 (lane quad*16); write ctx pre-split h/l
    float invl[4];
    #pragma unroll
    for (int r = 0; r < 4; r++) {
        const float lsum = __shfl(Oacc[4][r], lane & 48);   // broadcast from l16==0 lane
        invl[r] = 1.0f / lsum;
    }
    #pragma unroll
    for (int nt = 0; nt < 4; nt++) {
        #pragma unroll
        for (int r = 0; r < 4; r++) {
            const float v = Oacc[nt][r] * invl[r];
            const f16_t hh = (f16_t)v;
            const size_t o = (size_t)(b * S_ + q0 + wm + quad * 4 + r) * D_ + h * DH_ + nt * 16 + l16;
            ctxh[o] = hh;
            ctxl[o] = (f16_t)(v - (float)hh);
        }
    }
}

// ---------------- out[t] = LN(x[t] + y[t]) * g + b
__global__ __launch_bounds__(256) void add_ln_kernel(
    const float* __restrict__ x, const float* __restrict__ y,
    const float* __restrict__ g, const float* __restrict__ bb,
    float* __restrict__ out)
{
    const int t = blockIdx.x;
    const int tid = threadIdx.x;
    __shared__ float red[256];
    float vals[3];
    float lsum = 0.f;
    #pragma unroll
    for (int i = 0; i < 3; i++) {
        int c = tid + i * 256;
        float v = x[(size_t)t * D_ + c] + y[(size_t)t * D_ + c];
        vals[i] = v; lsum += v;
    }
    red[tid] = lsum; __syncthreads();
    for (int off = 128; off > 0; off >>= 1) { if (tid < off) red[tid] += red[tid + off]; __syncthreads(); }
    const float mu = red[0] * (1.0f / D_);
    __syncthreads();
    float lvar = 0.f;
    #pragma unroll
    for (int i = 0; i < 3; i++) { float d = vals[i] - mu; lvar += d * d; }
    red[tid] = lvar; __syncthreads();
    for (int off = 128; off > 0; off >>= 1) { if (tid < off) red[tid] += red[tid + off]; __syncthreads(); }
    const float rstd = rsqrtf(red[0] * (1.0f / D_) + 1e-12f);
    #pragma unroll
    for (int i = 0; i < 3; i++) {
        int c = tid + i * 256;
        out[(size_t)t * D_ + c] = (vals[i] - mu) * rstd * g[c] + bb[c];
    }
}

// ---------------- router: 1 wave per token
__global__ __launch_bounds__(64) void router_kernel(
    const float* __restrict__ att, const float* __restrict__ Wr,
    const float* __restrict__ br, float* __restrict__ gate, int* __restrict__ eidx)
{
    const int t = blockIdx.x;
    const int lane = threadIdx.x;
    float lg[E_] = {};
    for (int d = lane; d < D_; d += 64) {
        float xv = att[(size_t)t * D_ + d];
        #pragma unroll
        for (int e = 0; e < E_; e++) lg[e] += xv * Wr[d * E_ + e];
    }
    #pragma unroll
    for (int off = 32; off > 0; off >>= 1)
        #pragma unroll
        for (int e = 0; e < E_; e++) lg[e] += __shfl_down(lg[e], off);
    if (lane == 0) {
        float mx = -1e30f; int mi = 0;
        #pragma unroll
        for (int e = 0; e < E_; e++) {
            lg[e] += br[e];
            if (lg[e] > mx) { mx = lg[e]; mi = e; }
        }
        float ssum = 0.f;
        #pragma unroll
        for (int e = 0; e < E_; e++) ssum += expf(lg[e] - mx);
        gate[t] = 1.0f / ssum;
        eidx[t] = mi;
    }
}

// ---------------- position-within-expert scan (single block) + per-expert counts
__global__ __launch_bounds__(256) void pos_scan_kernel(
    const int* __restrict__ eidx, const float* __restrict__ gate,
    int* __restrict__ pos, float* __restrict__ scale, int* __restrict__ cnt_out)
{
    __shared__ int cnt[256][E_];
    const int tid = threadIdx.x;
    const int start = tid * (T_ / 256);
    int lc[E_] = {};
    for (int i = 0; i < T_ / 256; i++) lc[eidx[start + i]]++;
    #pragma unroll
    for (int e = 0; e < E_; e++) cnt[tid][e] = lc[e];
    __syncthreads();
    if (tid < E_) {
        int run = 0;
        for (int i = 0; i < 256; i++) { int c = cnt[i][tid]; cnt[i][tid] = run; run += c; }
        cnt_out[tid] = run;
    }
    __syncthreads();
    int off[E_];
    #pragma unroll
    for (int e = 0; e < E_; e++) off[e] = cnt[tid][e];
    for (int i = 0; i < T_ / 256; i++) {
        int tk = start + i;
        int e = eidx[tk];
        int p = off[e]++;
        bool keep = p < CAP_;
        pos[tk] = p < CAP_ - 1 ? p : CAP_ - 1;
        scale[tk] = keep ? gate[tk] : 0.0f;
    }
}

// ---------------- scatter kept tokens into per-expert bf16 buffers
__global__ __launch_bounds__(256) void scatter_kernel(
    const float* __restrict__ att, const int* __restrict__ eidx,
    const int* __restrict__ pos, const float* __restrict__ scale,
    bf16_t* __restrict__ buf)
{
    const int t = blockIdx.x;
    if (scale[t] == 0.0f) return;
    const int tid = threadIdx.x;
    const float* src = att + (size_t)t * D_;
    bf16_t* dst = buf + ((size_t)eidx[t] * CAP_ + pos[t]) * D_;
    for (int i = tid; i < D_; i += 256) dst[i] = (bf16_t)src[i];
}

// ---------------- gather (bf16 y) + residual + final LN
__global__ __launch_bounds__(256) void final_ln_kernel(
    const float* __restrict__ att, const bf16_t* __restrict__ y,
    const int* __restrict__ eidx, const int* __restrict__ pos,
    const float* __restrict__ scale,
    const float* __restrict__ g, const float* __restrict__ bb,
    float* __restrict__ out)
{
    const int t = blockIdx.x;
    const int tid = threadIdx.x;
    __shared__ float red[256];
    const float sc = scale[t];
    const bf16_t* yrow = y + ((size_t)eidx[t] * CAP_ + pos[t]) * D_;
    float vals[3];
    float lsum = 0.f;
    #pragma unroll
    for (int i = 0; i < 3; i++) {
        int c = tid + i * 256;
        float v = att[(size_t)t * D_ + c] + (float)yrow[c] * sc;
        vals[i] = v; lsum += v;
    }
    red[tid] = lsum; __syncthreads();
    for (int off = 128; off > 0; off >>= 1) { if (tid < off) red[tid] += red[tid + off]; __syncthreads(); }
    const float mu = red[0] * (1.0f / D_);
    __syncthreads();
    float lvar = 0.f;
    #pragma unroll
    for (int i = 0; i < 3; i++) { float d = vals[i] - mu; lvar += d * d; }
    red[tid] = lvar; __syncthreads();
    for (int off = 128; off > 0; off >>= 1) { if (tid < off) red[tid] += red[tid + off]; __syncthreads(); }
    const float rstd = rsqrtf(red[0] * (1.0f / D_) + 1e-12f);
    #pragma unroll
    for (int i = 0; i < 3; i++) {
        int c = tid + i * 256;
        out[(size_t)t * D_ + c] = (vals[i] - mu) * rstd * g[c] + bb[c];
    }
}

extern "C" void kernel_launch(void* const* d_in, const int* in_sizes, int n_in,
                              void* d_out, int out_size, void* d_ws, size_t ws_size,
                              hipStream_t stream) {
    const float* x     = (const float*)d_in[0];
    const float* mask  = (const float*)d_in[1];
    const float* Wq    = (const float*)d_in[2];
    const float* bq    = (const float*)d_in[3];
    const float* Wk    = (const float*)d_in[4];
    const float* bk    = (const float*)d_in[5];
    const float* Wv    = (const float*)d_in[6];
    const float* bv    = (const float*)d_in[7];
    const float* Wo    = (const float*)d_in[8];
    const float* bo    = (const float*)d_in[9];
    const float* ln1g  = (const float*)d_in[10];
    const float* ln1b  = (const float*)d_in[11];
    const float* Wr    = (const float*)d_in[12];
    const float* br    = (const float*)d_in[13];
    const float* W1    = (const float*)d_in[14];
    const float* b1    = (const float*)d_in[15];
    const float* W2    = (const float*)d_in[16];
    const float* b2    = (const float*)d_in[17];
    const float* ln2g  = (const float*)d_in[18];
    const float* ln2b  = (const float*)d_in[19];
    float* out = (float*)d_out;

    char* ws = (char*)d_ws;
    const size_t TDB = (size_t)T_ * D_ * 4;              // 25.17 MB
    // ---- attention-phase layout:
    f16_t* qkh  = (f16_t*)(ws);                          // [T,1536] f16  (= TDB bytes)
    f16_t* qkl  = (f16_t*)(ws + TDB);
    f16_t* vth  = (f16_t*)(ws + 2 * TDB);                // [B*H*64, S] f16 (= TDB/2)
    f16_t* vtl  = (f16_t*)(ws + 2 * TDB + TDB / 2);
    f16_t* ctxh = (f16_t*)(ws + 3 * TDB);                // [T,768] f16 (= TDB/2)
    f16_t* ctxl = (f16_t*)(ws + 3 * TDB + TDB / 2);
    float* att_buf = (float*)(ws + 4 * TDB);
    // xh/xl share the ctx slot (dead until flash writes it; GEMM reads xh first)
    f16_t* xh = (f16_t*)(ws + 3 * TDB);
    f16_t* xl = xh + (size_t)T_ * D_;
    // weight splits live in the att slot (att written only at add_ln)
    f16_t* wqkvT_h = (f16_t*)(ws + 4 * TDB);             // [2304,768] f16
    f16_t* wqkvT_l = wqkvT_h + (size_t)QKVSTR * D_;
    f16_t* woT_h   = wqkvT_l + (size_t)QKVSTR * D_;      // [768,768] f16
    f16_t* woT_l   = woT_h + (size_t)D_ * D_;            // total 9.4 MB < TDB
    // proj overlays qkh (dead after flash)
    float* proj_b = (float*)(ws);
    // MoE-phase overlays (dead attention regions):
    bf16_t* W1T = (bf16_t*)(ws);                         // [0, 1.5 TDB)
    bf16_t* W2T = (bf16_t*)(ws + (size_t)E_ * FF_ * D_ * 2);   // [1.5, 3 TDB)
    bf16_t* h_b = (bf16_t*)(ws + (size_t)2 * E_ * FF_ * D_ * 2); // [3, 4 TDB) (2-expert path)
    char*  smallp  = ws + 5 * TDB;
    float* gate_b  = (float*)(smallp);
    int*   eidx_b  = (int*)(smallp + 32768);
    int*   pos_b   = (int*)(smallp + 2 * 32768);
    float* scale_b = (float*)(smallp + 3 * 32768);
    int*   cnt_b   = (int*)(smallp + 4 * 32768);
    bf16_t* buf_b  = (bf16_t*)(smallp + 4 * 32768 + 128);
    bf16_t* y_b    = (bf16_t*)((char*)buf_b + (size_t)E_ * CAP_ * D_ * 2);
    // full-8-expert h buffer (used only if workspace is large enough)
    bf16_t* h8_b   = (bf16_t*)((char*)y_b + (size_t)E_ * CAP_ * D_ * 2);
    const size_t need8 = ((char*)h8_b - ws) + (size_t)E_ * CAP_ * FF_ * 2;

    dim3 blk(256);
    // ---- attention path (split-f16 MFMA, fp32-equivalent precision — feeds the router)
    cast_split_kernel<<<dim3(T_ * D_ / 1024), blk, 0, stream>>>(x, xh, xl);
    transpose_cast_split4_kernel<<<dim3(D_ / 32, D_ / 32, 4), blk, 0, stream>>>(
        Wq, Wk, Wv, Wo, wqkvT_h, wqkvT_l, woT_h, woT_l);
    // QKV GEMM -> split q/k rows + transposed split V (mode 1); 1-D XCD-chunked grid
    mfma_split_gemm_kernel<<<dim3((QKVSTR / 128) * (T_ / 128)), blk, 0, stream>>>(
        xh, xl, wqkvT_h, wqkvT_l, bq, bk, bv, nullptr, D_, QKVSTR,
        1, QKVSTR / 128, qkh, qkl, vth, vtl);
    flash_attn_mfma_kernel<<<dim3((S_ / 64) * H_ * B_), blk, 0, stream>>>(
        qkh, qkl, vth, vtl, mask, ctxh, ctxl);
    // proj GEMM (mode 0, fp32 out); 1-D XCD-chunked grid
    mfma_split_gemm_kernel<<<dim3((D_ / 128) * (T_ / 128)), blk, 0, stream>>>(
        ctxh, ctxl, woT_h, woT_l, bo, bo, bo, proj_b, D_, D_,
        0, D_ / 128, nullptr, nullptr, nullptr, nullptr);
    add_ln_kernel<<<dim3(T_), blk, 0, stream>>>(x, proj_b, ln1g, ln1b, att_buf);
    // ---- routing (fp32)
    router_kernel<<<dim3(T_), dim3(64), 0, stream>>>(att_buf, Wr, br, gate_b, eidx_b);
    pos_scan_kernel<<<dim3(1), blk, 0, stream>>>(eidx_b, gate_b, pos_b, scale_b, cnt_b);
    // ---- weight transpose-casts into dead attention region (safe after add_ln)
    transpose_cast_kernel<<<dim3(FF_ / 32, D_ / 32, E_), blk, 0, stream>>>(W1, W1T, D_, FF_);
    transpose_cast_kernel<<<dim3(D_ / 32, FF_ / 32, E_), blk, 0, stream>>>(W2, W2T, FF_, D_);
    // ---- expert buffers
    hipMemsetAsync(buf_b, 0, (size_t)E_ * CAP_ * D_ * 2, stream);
    scatter_kernel<<<dim3(T_), blk, 0, stream>>>(att_buf, eidx_b, pos_b, scale_b, buf_b);
    // ---- expert FFNs, bf16 MFMA
    if (ws_size >= need8) {
        // all 8 experts in two launches (full-machine grids, no serialization tails)
        mfma_gemm_kernel<<<dim3(FF_ / 128, CAP_ / 128, E_), blk, 0, stream>>>(
            buf_b, W1T, b1, h8_b,
            cnt_b, 0, CAP_, FF_, D_,
            (long)CAP_ * D_, (long)FF_ * D_, (long)FF_, (long)CAP_ * FF_, 1);
        mfma_gemm_kernel<<<dim3(D_ / 128, CAP_ / 128, E_), blk, 0, stream>>>(
            h8_b, W2T, b2, y_b,
            cnt_b, 0, CAP_, D_, FF_,
            (long)CAP_ * FF_, (long)D_ * FF_, (long)D_, (long)CAP_ * D_, 0);
    } else {
        for (int bch = 0; bch < 4; bch++) {
            const int e0 = bch * 2;
            mfma_gemm_kernel<<<dim3(FF_ / 128, CAP_ / 128, 2), blk, 0, stream>>>(
                buf_b + (size_t)e0 * CAP_ * D_, W1T + (size_t)e0 * FF_ * D_,
                b1 + (size_t)e0 * FF_, h_b,
                cnt_b, e0, CAP_, FF_, D_,
                (long)CAP_ * D_, (long)FF_ * D_, (long)FF_, (long)CAP_ * FF_, 1);
            mfma_gemm_kernel<<<dim3(D_ / 128, CAP_ / 128, 2), blk, 0, stream>>>(
                h_b, W2T + (size_t)e0 * D_ * FF_,
                b2 + (size_t)e0 * D_, y_b + (size_t)e0 * CAP_ * D_,
                cnt_b, e0, CAP_, D_, FF_,
                (long)CAP_ * FF_, (long)D_ * FF_, (long)D_, (long)CAP_ * D_, 0);
        }
    }
    // ---- gather + residual + LN2
    final_ln_kernel<<<dim3(T_), blk, 0, stream>>>(att_buf, y_b, eidx_b, pos_b, scale_b, ln2g, ln2b, out);
}

// Round 8
// 787.339 us; speedup vs baseline: 1.1194x; 1.0347x over previous
//
#include <hip/hip_runtime.h>
#include <hip/hip_bf16.h>
#include <math.h>

#define B_ 8
#define S_ 1024
#define D_ 768
#define H_ 12
#define DH_ 64
#define FF_ 3072
#define E_ 8
#define CAP_ 2048
#define T_ (B_ * S_)
#define QKVSTR 2304   // fused qkv col count
#define QKSTR 1536    // split q/k row stride

typedef __bf16 bf16_t;
typedef bf16_t bf16x8_t __attribute__((ext_vector_type(8)));
typedef bf16_t bf16x4_t __attribute__((ext_vector_type(4)));
typedef float floatx4_t __attribute__((ext_vector_type(4)));
typedef _Float16 f16_t;
typedef f16_t f16x8_t __attribute__((ext_vector_type(8)));
typedef f16_t f16x4_t __attribute__((ext_vector_type(4)));

// async global->LDS, 16B per lane; LDS dest = wave-uniform base + lane*16
__device__ __forceinline__ void gload_lds16(const void* g, void* l) {
    __builtin_amdgcn_global_load_lds(
        (const __attribute__((address_space(1))) unsigned int*)g,
        (__attribute__((address_space(3))) unsigned int*)l,
        16, 0, 0);
}

// ---------------- bf16 MFMA GEMM: C[M,N] = A[M,K] @ Bt[N,K]^T + bias (opt GELU), bf16 out
// Staging via global_load_lds (linear LDS [128][32], no pad).
__global__ __launch_bounds__(256) void mfma_gemm_kernel(
    const bf16_t* __restrict__ Abase, const bf16_t* __restrict__ Btbase,
    const float* __restrict__ biasbase, bf16_t* __restrict__ Cbase,
    const int* __restrict__ cnt, int cnt_off,
    int M, int N, int K,
    long strideAz, long strideBz, long strideBiasz, long strideCz,
    int apply_gelu)
{
    __shared__ bf16_t As[128 * 32];
    __shared__ bf16_t Bs[128 * 32];
    const int z = blockIdx.z;
    const int row0 = blockIdx.y * 128;
    const int col0 = blockIdx.x * 128;
    if (cnt && row0 >= cnt[cnt_off + z]) return;
    const bf16_t* A  = Abase + (size_t)z * strideAz;
    const bf16_t* Bt = Btbase + (size_t)z * strideBz;
    const float* bias = biasbase + (size_t)z * strideBiasz;
    bf16_t* C = Cbase + (size_t)z * strideCz;

    const int tid = threadIdx.x;
    const int lane = tid & 63, wave = tid >> 6;
    const int wm = (wave >> 1) * 64, wn = (wave & 1) * 64;
    const int l16 = lane & 15, quad = lane >> 4;
    const int gr = lane >> 2, gc = (lane & 3) * 8;   // staging: 16 rows/wave-issue

    floatx4_t acc[4][4] = {};

    for (int k0 = 0; k0 < K; k0 += 32) {
        __syncthreads();
        #pragma unroll
        for (int j = 0; j < 2; j++) {
            const int tr = wave * 32 + j * 16;
            gload_lds16(&A[(size_t)(row0 + tr + gr) * K + k0 + gc], &As[tr * 32]);
            gload_lds16(&Bt[(size_t)(col0 + tr + gr) * K + k0 + gc], &Bs[tr * 32]);
        }
        __syncthreads();   // compiler drains vmcnt before s_barrier
        bf16x8_t a[4], b[4];
        #pragma unroll
        for (int mt = 0; mt < 4; mt++)
            a[mt] = *(bf16x8_t*)&As[(wm + mt * 16 + l16) * 32 + quad * 8];
        #pragma unroll
        for (int nt = 0; nt < 4; nt++)
            b[nt] = *(bf16x8_t*)&Bs[(wn + nt * 16 + l16) * 32 + quad * 8];
        #pragma unroll
        for (int mt = 0; mt < 4; mt++)
            #pragma unroll
            for (int nt = 0; nt < 4; nt++)
                acc[mt][nt] = __builtin_amdgcn_mfma_f32_16x16x32_bf16(a[mt], b[nt], acc[mt][nt], 0, 0, 0);
    }

    #pragma unroll
    for (int mt = 0; mt < 4; mt++) {
        #pragma unroll
        for (int nt = 0; nt < 4; nt++) {
            const int col = col0 + wn + nt * 16 + l16;
            const float bv = bias[col];
            #pragma unroll
            for (int r = 0; r < 4; r++) {
                const int row = row0 + wm + mt * 16 + quad * 4 + r;
                float v = acc[mt][nt][r] + bv;
                if (apply_gelu) v = 0.5f * v * (1.0f + erff(v * 0.70710678118654752f));
                C[(size_t)row * N + col] = (bf16_t)v;
            }
        }
    }
}

// ---------------- split-f16 MFMA GEMM (fp32-equivalent): acc = (Ah+Al)@(Bth+Btl)^T / 64 + bias
// 1-D grid with XCD-chunk swizzle; staging via global_load_lds (linear LDS).
__global__ __launch_bounds__(256) void mfma_split_gemm_kernel(
    const f16_t* __restrict__ Ah, const f16_t* __restrict__ Al,
    const f16_t* __restrict__ Bth, const f16_t* __restrict__ Btl,
    const float* __restrict__ bias0, const float* __restrict__ bias1,
    const float* __restrict__ bias2,
    float* __restrict__ C, int K, int N, int mode, int nbx,
    f16_t* __restrict__ qkh, f16_t* __restrict__ qkl,
    f16_t* __restrict__ vth, f16_t* __restrict__ vtl)
{
    __shared__ f16_t Ash[128 * 32], Asl[128 * 32];
    __shared__ f16_t Bsh[128 * 32], Bsl[128 * 32];
    // XCD-chunk decode (gridDim.x divisible by 8)
    const int chunk = gridDim.x >> 3;
    const int p = blockIdx.x;
    const int orig = (p & 7) * chunk + (p >> 3);
    const int bx = orig % nbx, by = orig / nbx;
    const int row0 = by * 128;
    const int col0 = bx * 128;

    const int tid = threadIdx.x;
    const int lane = tid & 63, wave = tid >> 6;
    const int wm = (wave >> 1) * 64, wn = (wave & 1) * 64;
    const int l16 = lane & 15, quad = lane >> 4;
    const int gr = lane >> 2, gc = (lane & 3) * 8;

    floatx4_t acc[4][4] = {};

    for (int k0 = 0; k0 < K; k0 += 32) {
        __syncthreads();
        #pragma unroll
        for (int j = 0; j < 2; j++) {
            const int tr = wave * 32 + j * 16;
            const size_t ga = (size_t)(row0 + tr + gr) * K + k0 + gc;
            const size_t gb = (size_t)(col0 + tr + gr) * K + k0 + gc;
            gload_lds16(&Ah[ga], &Ash[tr * 32]);
            gload_lds16(&Al[ga], &Asl[tr * 32]);
            gload_lds16(&Bth[gb], &Bsh[tr * 32]);
            gload_lds16(&Btl[gb], &Bsl[tr * 32]);
        }
        __syncthreads();
        f16x8_t bh[4], bl[4];
        #pragma unroll
        for (int nt = 0; nt < 4; nt++) {
            bh[nt] = *(f16x8_t*)&Bsh[(wn + nt * 16 + l16) * 32 + quad * 8];
            bl[nt] = *(f16x8_t*)&Bsl[(wn + nt * 16 + l16) * 32 + quad * 8];
        }
        #pragma unroll
        for (int mt = 0; mt < 4; mt++) {
            f16x8_t ah = *(f16x8_t*)&Ash[(wm + mt * 16 + l16) * 32 + quad * 8];
            f16x8_t al = *(f16x8_t*)&Asl[(wm + mt * 16 + l16) * 32 + quad * 8];
            #pragma unroll
            for (int nt = 0; nt < 4; nt++) {
                acc[mt][nt] = __builtin_amdgcn_mfma_f32_16x16x32_f16(ah, bh[nt], acc[mt][nt], 0, 0, 0);
                acc[mt][nt] = __builtin_amdgcn_mfma_f32_16x16x32_f16(al, bh[nt], acc[mt][nt], 0, 0, 0);
                acc[mt][nt] = __builtin_amdgcn_mfma_f32_16x16x32_f16(ah, bl[nt], acc[mt][nt], 0, 0, 0);
            }
        }
    }

    const int wsel = col0 / 768;
    const float* bias = (wsel == 0) ? bias0 : (wsel == 1) ? bias1 : bias2;
    const int colsub = col0 % 768;

    if (mode == 1) {
        if (col0 < 1536) {
            // Q/K: split-f16 rows [T,1536]
            #pragma unroll
            for (int mt = 0; mt < 4; mt++) {
                #pragma unroll
                for (int nt = 0; nt < 4; nt++) {
                    const int col = col0 + wn + nt * 16 + l16;
                    const float bv = bias[colsub + wn + nt * 16 + l16];
                    #pragma unroll
                    for (int r = 0; r < 4; r++) {
                        const int row = row0 + wm + mt * 16 + quad * 4 + r;
                        float v = acc[mt][nt][r] * (1.0f / 64.0f) + bv;
                        f16_t hh = (f16_t)v;
                        const size_t o = (size_t)row * QKSTR + col;
                        qkh[o] = hh; qkl[o] = (f16_t)(v - (float)hh);
                    }
                }
            }
        } else {
            // V: transposed per (b,h): vt[((b*H+h)*64+d)*S + s]
            #pragma unroll
            for (int mt = 0; mt < 4; mt++) {
                const int rowb = row0 + wm + mt * 16 + quad * 4;
                const int bb = rowb >> 10, ss = rowb & 1023;
                #pragma unroll
                for (int nt = 0; nt < 4; nt++) {
                    const int d = (col0 - 1536) + wn + nt * 16 + l16;
                    const int hidx = d >> 6, dd = d & 63;
                    const float bv = bias[colsub + wn + nt * 16 + l16];
                    f16x4_t hv, lv;
                    #pragma unroll
                    for (int r = 0; r < 4; r++) {
                        float v = acc[mt][nt][r] * (1.0f / 64.0f) + bv;
                        hv[r] = (f16_t)v; lv[r] = (f16_t)(v - (float)hv[r]);
                    }
                    const size_t o = ((size_t)(bb * H_ + hidx) * DH_ + dd) * S_ + ss;
                    *(f16x4_t*)&vth[o] = hv;
                    *(f16x4_t*)&vtl[o] = lv;
                }
            }
        }
    } else {
        #pragma unroll
        for (int mt = 0; mt < 4; mt++) {
            #pragma unroll
            for (int nt = 0; nt < 4; nt++) {
                const int col = col0 + wn + nt * 16 + l16;
                const float bv = bias[colsub + wn + nt * 16 + l16];
                #pragma unroll
                for (int r = 0; r < 4; r++) {
                    const int row = row0 + wm + mt * 16 + quad * 4 + r;
                    C[(size_t)row * N + col] = acc[mt][nt][r] * (1.0f / 64.0f) + bv;
                }
            }
        }
    }
}

// ---------------- cast fp32 -> f16 hi/lo split (no scale)
__global__ __launch_bounds__(256) void cast_split_kernel(
    const float* __restrict__ src, f16_t* __restrict__ hi, f16_t* __restrict__ lo)
{
    const int i = blockIdx.x * 256 + threadIdx.x;   // each handles 4 floats
    float4 v = ((const float4*)src)[i];
    const float vv[4] = {v.x, v.y, v.z, v.w};
    f16x4_t h, l;
    #pragma unroll
    for (int c = 0; c < 4; c++) {
        f16_t hh = (f16_t)vv[c];
        h[c] = hh; l[c] = (f16_t)(vv[c] - (float)hh);
    }
    ((f16x4_t*)hi)[i] = h;
    ((f16x4_t*)lo)[i] = l;
}

// ---------------- fused 4-way transpose + scale(x64) + f16 hi/lo split (768x768 each):
// z=0..2: Wq/Wk/Wv -> wqkvT + z*D*D ; z=3: Wo -> woT
__global__ __launch_bounds__(256) void transpose_cast_split4_kernel(
    const float* __restrict__ Wq, const float* __restrict__ Wk,
    const float* __restrict__ Wv, const float* __restrict__ Wo,
    f16_t* __restrict__ wqkvT_h, f16_t* __restrict__ wqkvT_l,
    f16_t* __restrict__ woT_h, f16_t* __restrict__ woT_l)
{
    __shared__ float tile[32][33];
    const int z = blockIdx.z;
    const float* src = (z == 0) ? Wq : (z == 1) ? Wk : (z == 2) ? Wv : Wo;
    f16_t* dsth = (z < 3) ? wqkvT_h + (size_t)z * D_ * D_ : woT_h;
    f16_t* dstl = (z < 3) ? wqkvT_l + (size_t)z * D_ * D_ : woT_l;
    const int r0 = blockIdx.y * 32, c0 = blockIdx.x * 32;
    const int tid = threadIdx.x;
    const int tr = tid >> 3, tc4 = (tid & 7) * 4;
    float4 v = *(const float4*)&src[(size_t)(r0 + tr) * D_ + c0 + tc4];
    tile[tr][tc4 + 0] = v.x * 64.0f; tile[tr][tc4 + 1] = v.y * 64.0f;
    tile[tr][tc4 + 2] = v.z * 64.0f; tile[tr][tc4 + 3] = v.w * 64.0f;
    __syncthreads();
    const int cc = tid >> 3, rr4 = (tid & 7) * 4;
    f16x4_t h, l;
    #pragma unroll
    for (int i = 0; i < 4; i++) {
        float f = tile[rr4 + i][cc];
        f16_t hh = (f16_t)f;
        h[i] = hh; l[i] = (f16_t)(f - (float)hh);
    }
    *(f16x4_t*)&dsth[(size_t)(c0 + cc) * D_ + r0 + rr4] = h;
    *(f16x4_t*)&dstl[(size_t)(c0 + cc) * D_ + r0 + rr4] = l;
}

// ---------------- transpose + cast: fp32 src[R,C] -> bf16 dst[C,R], z-batched
__global__ __launch_bounds__(256) void transpose_cast_kernel(
    const float* __restrict__ src, bf16_t* __restrict__ dst, int R, int C)
{
    __shared__ float tile[32][33];
    const size_t zoff = (size_t)blockIdx.z * R * C;
    const float* s = src + zoff;
    bf16_t* d = dst + zoff;
    const int r0 = blockIdx.y * 32, c0 = blockIdx.x * 32;
    const int tid = threadIdx.x;
    const int tr = tid >> 3, tc4 = (tid & 7) * 4;
    float4 v = *(const float4*)&s[(size_t)(r0 + tr) * C + c0 + tc4];
    tile[tr][tc4 + 0] = v.x; tile[tr][tc4 + 1] = v.y;
    tile[tr][tc4 + 2] = v.z; tile[tr][tc4 + 3] = v.w;
    __syncthreads();
    const int cc = tid >> 3, rr4 = (tid & 7) * 4;
    bf16x4_t o;
    #pragma unroll
    for (int i = 0; i < 4; i++) o[i] = (bf16_t)tile[rr4 + i][cc];
    *(bf16x4_t*)&d[(size_t)(c0 + cc) * R + r0 + rr4] = o;
}

// ---------------- flash attention v5b: v2 structure (KVB=64) + XCD-local grid +
// row-sum fused into PV via a constant ones-row in V (l accumulates in Oacc[4]
// with the same alpha rescale -> no rsum shuffles, no lrun bookkeeping).
#define FSTR 72   // LDS row stride (f16): 144 B rows

__global__ __launch_bounds__(256) void flash_attn_mfma_kernel(
    const f16_t* __restrict__ qkh, const f16_t* __restrict__ qkl,
    const f16_t* __restrict__ vth, const f16_t* __restrict__ vtl,
    const float* __restrict__ mask,
    f16_t* __restrict__ ctxh, f16_t* __restrict__ ctxl)
{
    __shared__ f16_t Kh[64 * FSTR], Kl[64 * FSTR];
    __shared__ f16_t Vh[80 * FSTR], Vl[80 * FSTR];   // rows 0-63 = d; row 64 = ones; 65-79 = 0
    __shared__ f16_t Ph[64 * FSTR], Pl[64 * FSTR];
    // XCD-local decode: all 16 q-tiles of one (b,h) land on the same XCD.
    const int flat = blockIdx.x;
    const int qt = (flat >> 3) & 15;
    const int p  = (flat & 7) + 8 * (flat >> 7);
    const int h = p % H_, b = p / H_;
    const int tid = threadIdx.x;
    const int lane = tid & 63, wave = tid >> 6;
    const int l16 = lane & 15, quad = lane >> 4;
    const int wm = wave * 16;           // wave's 16-query-row strip
    const int q0 = qt * 64;

    // ---- Q fragments in registers (wave-private rows wm..wm+15)
    const size_t qoff = (size_t)(b * S_ + q0 + wm + l16) * QKSTR + h * DH_ + quad * 8;
    f16x8_t qh[2], ql[2];
    qh[0] = *(const f16x8_t*)&qkh[qoff];
    qh[1] = *(const f16x8_t*)&qkh[qoff + 32];
    ql[0] = *(const f16x8_t*)&qkl[qoff];
    ql[1] = *(const f16x8_t*)&qkl[qoff + 32];

    // ---- ones-row region of V (rows 64-79): row 64 = 1.0 (h) / 0.0 (l); rows 65-79 = 0.
    #pragma unroll
    for (int i = 0; i < 4; i++) {
        int idx = i * 256 + tid;                 // 0..1023 = 16 rows x 64 cols
        int rr = 64 + (idx >> 6), cc = idx & 63;
        Vh[rr * FSTR + cc] = (rr == 64) ? (f16_t)1.0f : (f16_t)0.0f;
        Vl[rr * FSTR + cc] = (f16_t)0.0f;
    }

    // ---- staging geometry: 512 int4-chunks per buffer, 2 per thread
    const int r0 = tid >> 3, s0 = (tid & 7) * 8;          // rows 0..31
    const int r1 = r0 + 32, s1 = s0;                      // rows 32..63
    const size_t kbase = (size_t)b * S_ * QKSTR + 768 + (size_t)h * DH_;
    const size_t vbase = (size_t)(b * H_ + h) * DH_ * (size_t)S_;

    int4 kr0h, kr1h, kr0l, kr1l, vr0h, vr1h, vr0l, vr1l;
    auto prefetch = [&](int k0) {
        kr0h = *(const int4*)&qkh[kbase + (size_t)(k0 + r0) * QKSTR + s0];
        kr1h = *(const int4*)&qkh[kbase + (size_t)(k0 + r1) * QKSTR + s1];
        kr0l = *(const int4*)&qkl[kbase + (size_t)(k0 + r0) * QKSTR + s0];
        kr1l = *(const int4*)&qkl[kbase + (size_t)(k0 + r1) * QKSTR + s1];
        vr0h = *(const int4*)&vth[vbase + (size_t)r0 * S_ + k0 + s0];
        vr1h = *(const int4*)&vth[vbase + (size_t)r1 * S_ + k0 + s1];
        vr0l = *(const int4*)&vtl[vbase + (size_t)r0 * S_ + k0 + s0];
        vr1l = *(const int4*)&vtl[vbase + (size_t)r1 * S_ + k0 + s1];
    };
    prefetch(0);

    floatx4_t Oacc[5] = {};             // [0..3]: col = nt*16+l16 (=d); [4]: col0 = row-sum l
    float mrun[4];
    #pragma unroll
    for (int i = 0; i < 4; i++) mrun[i] = -1e30f;

    for (int kt = 0; kt < S_ / 64; kt++) {
        __syncthreads();   // prior K/V readers done
        *(int4*)&Kh[r0 * FSTR + s0] = kr0h;
        *(int4*)&Kh[r1 * FSTR + s1] = kr1h;
        *(int4*)&Kl[r0 * FSTR + s0] = kr0l;
        *(int4*)&Kl[r1 * FSTR + s1] = kr1l;
        *(int4*)&Vh[r0 * FSTR + s0] = vr0h;
        *(int4*)&Vh[r1 * FSTR + s1] = vr1h;
        *(int4*)&Vl[r0 * FSTR + s0] = vr0l;
        *(int4*)&Vl[r1 * FSTR + s1] = vr1l;
        __syncthreads();   // staged data visible
        if (kt + 1 < S_ / 64) prefetch((kt + 1) * 64);   // overlap with compute

        // ---- S = Q @ K^T, 3-product split
        floatx4_t sacc[4] = {};
        __builtin_amdgcn_s_setprio(1);
        #pragma unroll
        for (int ks2 = 0; ks2 < 2; ks2++) {
            const f16x8_t ah = qh[ks2], al = ql[ks2];
            #pragma unroll
            for (int nt = 0; nt < 4; nt++) {
                f16x8_t bh = *(f16x8_t*)&Kh[(nt * 16 + l16) * FSTR + ks2 * 32 + quad * 8];
                f16x8_t bl = *(f16x8_t*)&Kl[(nt * 16 + l16) * FSTR + ks2 * 32 + quad * 8];
                sacc[nt] = __builtin_amdgcn_mfma_f32_16x16x32_f16(ah, bh, sacc[nt], 0, 0, 0);
                sacc[nt] = __builtin_amdgcn_mfma_f32_16x16x32_f16(al, bh, sacc[nt], 0, 0, 0);
                sacc[nt] = __builtin_amdgcn_mfma_f32_16x16x32_f16(ah, bl, sacc[nt], 0, 0, 0);
            }
        }
        __builtin_amdgcn_s_setprio(0);

        const int k0 = kt * 64;
        float mk[4];
        #pragma unroll
        for (int nt = 0; nt < 4; nt++) mk[nt] = mask[b * S_ + k0 + nt * 16 + l16];

        // ---- online softmax (rows wm+quad*4+r, wave-private), P split to LDS
        #pragma unroll
        for (int r = 0; r < 4; r++) {
            float s[4];
            float rmax = -1e30f;
            #pragma unroll
            for (int nt = 0; nt < 4; nt++) {
                s[nt] = sacc[nt][r] * 0.125f + mk[nt];
                rmax = fmaxf(rmax, s[nt]);
            }
            #pragma unroll
            for (int off = 1; off < 16; off <<= 1) rmax = fmaxf(rmax, __shfl_xor(rmax, off));
            const float mnew = fmaxf(mrun[r], rmax);
            const float alpha = __expf(mrun[r] - mnew);
            mrun[r] = mnew;
            const int row = wm + quad * 4 + r;
            #pragma unroll
            for (int nt = 0; nt < 4; nt++) {
                float pv = __expf(s[nt] - mnew);
                f16_t ph = (f16_t)pv;
                Ph[row * FSTR + nt * 16 + l16] = ph;
                Pl[row * FSTR + nt * 16 + l16] = (f16_t)(pv - (float)ph);
            }
            #pragma unroll
            for (int nt = 0; nt < 5; nt++) Oacc[nt][r] *= alpha;
        }
        // P is wave-private (writer rows == reader rows) -> no barrier needed

        // ---- O += P @ V ; Oacc[4] accumulates the row-sum via the ones-row
        __builtin_amdgcn_s_setprio(1);
        #pragma unroll
        for (int ks2 = 0; ks2 < 2; ks2++) {
            f16x8_t ah = *(f16x8_t*)&Ph[(wm + l16) * FSTR + ks2 * 32 + quad * 8];
            f16x8_t al = *(f16x8_t*)&Pl[(wm + l16) * FSTR + ks2 * 32 + quad * 8];
            #pragma unroll
            for (int nt = 0; nt < 5; nt++) {
                f16x8_t bh = *(f16x8_t*)&Vh[(nt * 16 + l16) * FSTR + ks2 * 32 + quad * 8];
                Oacc[nt] = __builtin_amdgcn_mfma_f32_16x16x32_f16(ah, bh, Oacc[nt], 0, 0, 0);
                Oacc[nt] = __builtin_amdgcn_mfma_f32_16x16x32_f16(al, bh, Oacc[nt], 0, 0, 0);
                if (nt < 4) {   // ones-row low part is exactly 0 -> skip third product
                    f16x8_t bl = *(f16x8_t*)&Vl[(nt * 16 + l16) * FSTR + ks2 * 32 + quad * 8];
                    Oacc[nt] = __builtin_amdgcn_mfma_f32_16x16x32_f16(ah, bl, Oacc[nt], 0, 0, 0);
                }
            }
        }
        __builtin_amdgcn_s_setprio(0);
    }

    // ---- epilogue: l = Oacc[4] col 0 (lane quad*16); write ctx pre-split h/l
    float invl[4];
    #pragma unroll
    for (int r = 0; r < 4; r++) {
        const float lsum = __shfl(Oacc[4][r], lane & 48);   // broadcast from l16==0 lane
        invl[r] = 1.0f / lsum;
    }
    #pragma unroll
    for (int nt = 0; nt < 4; nt++) {
        #pragma unroll
        for (int r = 0; r < 4; r++) {
            const float v = Oacc[nt][r] * invl[r];
            const f16_t hh = (f16_t)v;
            const size_t o = (size_t)(b * S_ + q0 + wm + quad * 4 + r) * D_ + h * DH_ + nt * 16 + l16;
            ctxh[o] = hh;
            ctxl[o] = (f16_t)(v - (float)hh);
        }
    }
}

// ---------------- out[t] = LN(x[t] + y[t]) * g + b
__global__ __launch_bounds__(256) void add_ln_kernel(
    const float* __restrict__ x, const float* __restrict__ y,
    const float* __restrict__ g, const float* __restrict__ bb,
    float* __restrict__ out)
{
    const int t = blockIdx.x;
    const int tid = threadIdx.x;
    __shared__ float red[256];
    float vals[3];
    float lsum = 0.f;
    #pragma unroll
    for (int i = 0; i < 3; i++) {
        int c = tid + i * 256;
        float v = x[(size_t)t * D_ + c] + y[(size_t)t * D_ + c];
        vals[i] = v; lsum += v;
    }
    red[tid] = lsum; __syncthreads();
    for (int off = 128; off > 0; off >>= 1) { if (tid < off) red[tid] += red[tid + off]; __syncthreads(); }
    const float mu = red[0] * (1.0f / D_);
    __syncthreads();
    float lvar = 0.f;
    #pragma unroll
    for (int i = 0; i < 3; i++) { float d = vals[i] - mu; lvar += d * d; }
    red[tid] = lvar; __syncthreads();
    for (int off = 128; off > 0; off >>= 1) { if (tid < off) red[tid] += red[tid + off]; __syncthreads(); }
    const float rstd = rsqrtf(red[0] * (1.0f / D_) + 1e-12f);
    #pragma unroll
    for (int i = 0; i < 3; i++) {
        int c = tid + i * 256;
        out[(size_t)t * D_ + c] = (vals[i] - mu) * rstd * g[c] + bb[c];
    }
}

// ---------------- router: 1 wave per token
__global__ __launch_bounds__(64) void router_kernel(
    const float* __restrict__ att, const float* __restrict__ Wr,
    const float* __restrict__ br, float* __restrict__ gate, int* __restrict__ eidx)
{
    const int t = blockIdx.x;
    const int lane = threadIdx.x;
    float lg[E_] = {};
    for (int d = lane; d < D_; d += 64) {
        float xv = att[(size_t)t * D_ + d];
        #pragma unroll
        for (int e = 0; e < E_; e++) lg[e] += xv * Wr[d * E_ + e];
    }
    #pragma unroll
    for (int off = 32; off > 0; off >>= 1)
        #pragma unroll
        for (int e = 0; e < E_; e++) lg[e] += __shfl_down(lg[e], off);
    if (lane == 0) {
        float mx = -1e30f; int mi = 0;
        #pragma unroll
        for (int e = 0; e < E_; e++) {
            lg[e] += br[e];
            if (lg[e] > mx) { mx = lg[e]; mi = e; }
        }
        float ssum = 0.f;
        #pragma unroll
        for (int e = 0; e < E_; e++) ssum += expf(lg[e] - mx);
        gate[t] = 1.0f / ssum;
        eidx[t] = mi;
    }
}

// ---------------- position-within-expert scan (single block) + per-expert counts
__global__ __launch_bounds__(256) void pos_scan_kernel(
    const int* __restrict__ eidx, const float* __restrict__ gate,
    int* __restrict__ pos, float* __restrict__ scale, int* __restrict__ cnt_out)
{
    __shared__ int cnt[256][E_];
    const int tid = threadIdx.x;
    const int start = tid * (T_ / 256);
    int lc[E_] = {};
    for (int i = 0; i < T_ / 256; i++) lc[eidx[start + i]]++;
    #pragma unroll
    for (int e = 0; e < E_; e++) cnt[tid][e] = lc[e];
    __syncthreads();
    if (tid < E_) {
        int run = 0;
        for (int i = 0; i < 256; i++) { int c = cnt[i][tid]; cnt[i][tid] = run; run += c; }
        cnt_out[tid] = run;
    }
    __syncthreads();
    int off[E_];
    #pragma unroll
    for (int e = 0; e < E_; e++) off[e] = cnt[tid][e];
    for (int i = 0; i < T_ / 256; i++) {
        int tk = start + i;
        int e = eidx[tk];
        int p = off[e]++;
        bool keep = p < CAP_;
        pos[tk] = p < CAP_ - 1 ? p : CAP_ - 1;
        scale[tk] = keep ? gate[tk] : 0.0f;
    }
}

// ---------------- scatter kept tokens into per-expert bf16 buffers
__global__ __launch_bounds__(256) void scatter_kernel(
    const float* __restrict__ att, const int* __restrict__ eidx,
    const int* __restrict__ pos, const float* __restrict__ scale,
    bf16_t* __restrict__ buf)
{
    const int t = blockIdx.x;
    if (scale[t] == 0.0f) return;
    const int tid = threadIdx.x;
    const float* src = att + (size_t)t * D_;
    bf16_t* dst = buf + ((size_t)eidx[t] * CAP_ + pos[t]) * D_;
    for (int i = tid; i < D_; i += 256) dst[i] = (bf16_t)src[i];
}

// ---------------- gather (bf16 y) + residual + final LN
__global__ __launch_bounds__(256) void final_ln_kernel(
    const float* __restrict__ att, const bf16_t* __restrict__ y,
    const int* __restrict__ eidx, const int* __restrict__ pos,
    const float* __restrict__ scale,
    const float* __restrict__ g, const float* __restrict__ bb,
    float* __restrict__ out)
{
    const int t = blockIdx.x;
    const int tid = threadIdx.x;
    __shared__ float red[256];
    const float sc = scale[t];
    const bf16_t* yrow = y + ((size_t)eidx[t] * CAP_ + pos[t]) * D_;
    float vals[3];
    float lsum = 0.f;
    #pragma unroll
    for (int i = 0; i < 3; i++) {
        int c = tid + i * 256;
        float v = att[(size_t)t * D_ + c] + (float)yrow[c] * sc;
        vals[i] = v; lsum += v;
    }
    red[tid] = lsum; __syncthreads();
    for (int off = 128; off > 0; off >>= 1) { if (tid < off) red[tid] += red[tid + off]; __syncthreads(); }
    const float mu = red[0] * (1.0f / D_);
    __syncthreads();
    float lvar = 0.f;
    #pragma unroll
    for (int i = 0; i < 3; i++) { float d = vals[i] - mu; lvar += d * d; }
    red[tid] = lvar; __syncthreads();
    for (int off = 128; off > 0; off >>= 1) { if (tid < off) red[tid] += red[tid + off]; __syncthreads(); }
    const float rstd = rsqrtf(red[0] * (1.0f / D_) + 1e-12f);
    #pragma unroll
    for (int i = 0; i < 3; i++) {
        int c = tid + i * 256;
        out[(size_t)t * D_ + c] = (vals[i] - mu) * rstd * g[c] + bb[c];
    }
}

extern "C" void kernel_launch(void* const* d_in, const int* in_sizes, int n_in,
                              void* d_out, int out_size, void* d_ws, size_t ws_size,
                              hipStream_t stream) {
    const float* x     = (const float*)d_in[0];
    const float* mask  = (const float*)d_in[1];
    const float* Wq    = (const float*)d_in[2];
    const float* bq    = (const float*)d_in[3];
    const float* Wk    = (const float*)d_in[4];
    const float* bk    = (const float*)d_in[5];
    const float* Wv    = (const float*)d_in[6];
    const float* bv    = (const float*)d_in[7];
    const float* Wo    = (const float*)d_in[8];
    const float* bo    = (const float*)d_in[9];
    const float* ln1g  = (const float*)d_in[10];
    const float* ln1b  = (const float*)d_in[11];
    const float* Wr    = (const float*)d_in[12];
    const float* br    = (const float*)d_in[13];
    const float* W1    = (const float*)d_in[14];
    const float* b1    = (const float*)d_in[15];
    const float* W2    = (const float*)d_in[16];
    const float* b2    = (const float*)d_in[17];
    const float* ln2g  = (const float*)d_in[18];
    const float* ln2b  = (const float*)d_in[19];
    float* out = (float*)d_out;

    char* ws = (char*)d_ws;
    const size_t TDB = (size_t)T_ * D_ * 4;              // 25.17 MB
    // ---- attention-phase layout:
    f16_t* qkh  = (f16_t*)(ws);                          // [T,1536] f16  (= TDB bytes)
    f16_t* qkl  = (f16_t*)(ws + TDB);
    f16_t* vth  = (f16_t*)(ws + 2 * TDB);                // [B*H*64, S] f16 (= TDB/2)
    f16_t* vtl  = (f16_t*)(ws + 2 * TDB + TDB / 2);
    f16_t* ctxh = (f16_t*)(ws + 3 * TDB);                // [T,768] f16 (= TDB/2)
    f16_t* ctxl = (f16_t*)(ws + 3 * TDB + TDB / 2);
    float* att_buf = (float*)(ws + 4 * TDB);
    // xh/xl share the ctx slot (dead until flash writes it; GEMM reads xh first)
    f16_t* xh = (f16_t*)(ws + 3 * TDB);
    f16_t* xl = xh + (size_t)T_ * D_;
    // weight splits live in the att slot (att written only at add_ln)
    f16_t* wqkvT_h = (f16_t*)(ws + 4 * TDB);             // [2304,768] f16
    f16_t* wqkvT_l = wqkvT_h + (size_t)QKVSTR * D_;
    f16_t* woT_h   = wqkvT_l + (size_t)QKVSTR * D_;      // [768,768] f16
    f16_t* woT_l   = woT_h + (size_t)D_ * D_;            // total 9.4 MB < TDB
    // proj overlays qkh (dead after flash)
    float* proj_b = (float*)(ws);
    // MoE-phase overlays (dead attention regions):
    bf16_t* W1T = (bf16_t*)(ws);                         // [0, 1.5 TDB)
    bf16_t* W2T = (bf16_t*)(ws + (size_t)E_ * FF_ * D_ * 2);   // [1.5, 3 TDB)
    bf16_t* h_b = (bf16_t*)(ws + (size_t)2 * E_ * FF_ * D_ * 2); // [3, 4 TDB) (2-expert path)
    char*  smallp  = ws + 5 * TDB;
    float* gate_b  = (float*)(smallp);
    int*   eidx_b  = (int*)(smallp + 32768);
    int*   pos_b   = (int*)(smallp + 2 * 32768);
    float* scale_b = (float*)(smallp + 3 * 32768);
    int*   cnt_b   = (int*)(smallp + 4 * 32768);
    bf16_t* buf_b  = (bf16_t*)(smallp + 4 * 32768 + 128);
    bf16_t* y_b    = (bf16_t*)((char*)buf_b + (size_t)E_ * CAP_ * D_ * 2);
    // full-8-expert h buffer (used only if workspace is large enough)
    bf16_t* h8_b   = (bf16_t*)((char*)y_b + (size_t)E_ * CAP_ * D_ * 2);
    const size_t need8 = ((char*)h8_b - ws) + (size_t)E_ * CAP_ * FF_ * 2;

    dim3 blk(256);
    // ---- attention path (split-f16 MFMA, fp32-equivalent precision — feeds the router)
    cast_split_kernel<<<dim3(T_ * D_ / 1024), blk, 0, stream>>>(x, xh, xl);
    transpose_cast_split4_kernel<<<dim3(D_ / 32, D_ / 32, 4), blk, 0, stream>>>(
        Wq, Wk, Wv, Wo, wqkvT_h, wqkvT_l, woT_h, woT_l);
    // QKV GEMM -> split q/k rows + transposed split V (mode 1); 1-D XCD-chunked grid
    mfma_split_gemm_kernel<<<dim3((QKVSTR / 128) * (T_ / 128)), blk, 0, stream>>>(
        xh, xl, wqkvT_h, wqkvT_l, bq, bk, bv, nullptr, D_, QKVSTR,
        1, QKVSTR / 128, qkh, qkl, vth, vtl);
    flash_attn_mfma_kernel<<<dim3((S_ / 64) * H_ * B_), blk, 0, stream>>>(
        qkh, qkl, vth, vtl, mask, ctxh, ctxl);
    // proj GEMM (mode 0, fp32 out); 1-D XCD-chunked grid
    mfma_split_gemm_kernel<<<dim3((D_ / 128) * (T_ / 128)), blk, 0, stream>>>(
        ctxh, ctxl, woT_h, woT_l, bo, bo, bo, proj_b, D_, D_,
        0, D_ / 128, nullptr, nullptr, nullptr, nullptr);
    add_ln_kernel<<<dim3(T_), blk, 0, stream>>>(x, proj_b, ln1g, ln1b, att_buf);
    // ---- routing (fp32)
    router_kernel<<<dim3(T_), dim3(64), 0, stream>>>(att_buf, Wr, br, gate_b, eidx_b);
    pos_scan_kernel<<<dim3(1), blk, 0, stream>>>(eidx_b, gate_b, pos_b, scale_b, cnt_b);
    // ---- weight transpose-casts into dead attention region (safe after add_ln)
    transpose_cast_kernel<<<dim3(FF_ / 32, D_ / 32, E_), blk, 0, stream>>>(W1, W1T, D_, FF_);
    transpose_cast_kernel<<<dim3(D_ / 32, FF_ / 32, E_), blk, 0, stream>>>(W2, W2T, FF_, D_);
    // ---- expert buffers
    hipMemsetAsync(buf_b, 0, (size_t)E_ * CAP_ * D_ * 2, stream);
    scatter_kernel<<<dim3(T_), blk, 0, stream>>>(att_buf, eidx_b, pos_b, scale_b, buf_b);
    // ---- expert FFNs, bf16 MFMA
    if (ws_size >= need8) {
        // all 8 experts in two launches (full-machine grids, no serialization tails)
        mfma_gemm_kernel<<<dim3(FF_ / 128, CAP_ / 128, E_), blk, 0, stream>>>(
            buf_b, W1T, b1, h8_b,
            cnt_b, 0, CAP_, FF_, D_,
            (long)CAP_ * D_, (long)FF_ * D_, (long)FF_, (long)CAP_ * FF_, 1);
        mfma_gemm_kernel<<<dim3(D_ / 128, CAP_ / 128, E_), blk, 0, stream>>>(
            h8_b, W2T, b2, y_b,
            cnt_b, 0, CAP_, D_, FF_,
            (long)CAP_ * FF_, (long)D_ * FF_, (long)D_, (long)CAP_ * D_, 0);
    } else {
        for (int bch = 0; bch < 4; bch++) {
            const int e0 = bch * 2;
            mfma_gemm_kernel<<<dim3(FF_ / 128, CAP_ / 128, 2), blk, 0, stream>>>(
                buf_b + (size_t)e0 * CAP_ * D_, W1T + (size_t)e0 * FF_ * D_,
                b1 + (size_t)e0 * FF_, h_b,
                cnt_b, e0, CAP_, FF_, D_,
                (long)CAP_ * D_, (long)FF_ * D_, (long)FF_, (long)CAP_ * FF_, 1);
            mfma_gemm_kernel<<<dim3(D_ / 128, CAP_ / 128, 2), blk, 0, stream>>>(
                h_b, W2T + (size_t)e0 * D_ * FF_,
                b2 + (size_t)e0 * D_, y_b + (size_t)e0 * CAP_ * D_,
                cnt_b, e0, CAP_, D_, FF_,
                (long)CAP_ * FF_, (long)D_ * FF_, (long)D_, (long)CAP_ * D_, 0);
        }
    }
    // ---- gather + residual + LN2
    final_ln_kernel<<<dim3(T_), blk, 0, stream>>>(att_buf, y_b, eidx_b, pos_b, scale_b, ln2g, ln2b, out);
}